// Round 13
// baseline (284.968 us; speedup 1.0000x reference)
//
#include <hip/hip_runtime.h>
#include <math.h>

typedef __attribute__((ext_vector_type(8))) short short8;
typedef __attribute__((ext_vector_type(4))) float f32x4;
typedef unsigned short u16;
typedef unsigned int u32;

constexpr int Bb = 8;
constexpr int Nn = 9216;   // 96*96
constexpr int Cc = 256;    // = D
constexpr int Oo = 512;    // 2C
constexpr float LN_EPS = 1e-5f;
constexpr int KS2 = 16;    // ctx GEMM split-K chunks (9216 = 16*576)

static __device__ __forceinline__ u16 f2bf(float f) {
    unsigned u = __builtin_bit_cast(unsigned, f);
    u += 0x7fffu + ((u >> 16) & 1u);   // RNE
    return (u16)(u >> 16);
}
static __device__ __forceinline__ float bf2f(u16 u) {
    return __builtin_bit_cast(float, (unsigned)u << 16);
}

// ---------------- K_pre v3: fused per-input pass (512 threads, 64n x 256d per block).
__global__ __launch_bounds__(512, 2) void k_pre(const float* __restrict__ src,
                                                const float* __restrict__ lnw,
                                                const float* __restrict__ lnb,
                                                u16* __restrict__ dstT,
                                                u16* __restrict__ Qexp,
                                                float* __restrict__ pS,
                                                int doExp) {
    __shared__ u16 tile[256][66];    // [d][n], pad 66 (132 B rows)
    __shared__ float wsh[256], bsh[256];
    const int b = blockIdx.z;
    const int nc = (blockIdx.x & 7) * 18 + (blockIdx.x >> 3);   // XCD swizzle (144 = 8*18)
    const int n0 = nc * 64;
    const int t = threadIdx.x;
    if (t < 256) { wsh[t] = lnw[t]; bsh[t] = lnb[t]; }
    __syncthreads();

    const int r = t >> 3;            // 0..63
    const int g = t & 7;             // 0..7
    const long long row = (long long)b * Nn + n0 + r;
    const float* rowp = src + row * Cc;

    float4 v[8];
#pragma unroll
    for (int i = 0; i < 8; ++i)
        v[i] = *reinterpret_cast<const float4*>(rowp + g * 4 + i * 32);

    float s = 0.f, q = 0.f;
#pragma unroll
    for (int i = 0; i < 8; ++i) {
        s += v[i].x + v[i].y + v[i].z + v[i].w;
        q += v[i].x * v[i].x + v[i].y * v[i].y + v[i].z * v[i].z + v[i].w * v[i].w;
    }
    s += __shfl_xor(s, 1); s += __shfl_xor(s, 2); s += __shfl_xor(s, 4);
    q += __shfl_xor(q, 1); q += __shfl_xor(q, 2); q += __shfl_xor(q, 4);
    const float mu = s * (1.0f / Cc);
    const float rstd = rsqrtf(q * (1.0f / Cc) - mu * mu + LN_EPS);

    float se = 0.f;
#pragma unroll
    for (int i = 0; i < 8; ++i) {
        const int d = g * 4 + i * 32;
        const float4 w4 = *reinterpret_cast<const float4*>(&wsh[d]);
        const float4 b4 = *reinterpret_cast<const float4*>(&bsh[d]);
        v[i].x = (v[i].x - mu) * rstd * w4.x + b4.x;
        v[i].y = (v[i].y - mu) * rstd * w4.y + b4.y;
        v[i].z = (v[i].z - mu) * rstd * w4.z + b4.z;
        v[i].w = (v[i].w - mu) * rstd * w4.w + b4.w;
        if (doExp) {
            v[i].x = __expf(v[i].x); v[i].y = __expf(v[i].y);
            v[i].z = __expf(v[i].z); v[i].w = __expf(v[i].w);
            se += v[i].x + v[i].y + v[i].z + v[i].w;
        }
        tile[d + 0][r] = f2bf(v[i].x);
        tile[d + 1][r] = f2bf(v[i].y);
        tile[d + 2][r] = f2bf(v[i].z);
        tile[d + 3][r] = f2bf(v[i].w);
    }

    if (doExp) {
        se += __shfl_xor(se, 1); se += __shfl_xor(se, 2); se += __shfl_xor(se, 4);
        const float inv = 1.0f / se;
#pragma unroll
        for (int i = 0; i < 8; ++i) {
            const int d = g * 4 + i * 32;
            int2 pk;
            pk.x = (int)((unsigned)f2bf(v[i].x * inv) | ((unsigned)f2bf(v[i].y * inv) << 16));
            pk.y = (int)((unsigned)f2bf(v[i].z * inv) | ((unsigned)f2bf(v[i].w * inv) << 16));
            *reinterpret_cast<int2*>(Qexp + row * Cc + d) = pk;
        }
    }
    __syncthreads();

    // transposed global write (4x b32 reads: 132-B rows keep 4-B alignment)
#pragma unroll
    for (int p = 0; p < 4; ++p) {
        const int d = p * 64 + (t >> 3);
        const int c = (t & 7) * 8;
        int4 u;
        u.x = (int)*reinterpret_cast<const u32*>(&tile[d][c + 0]);
        u.y = (int)*reinterpret_cast<const u32*>(&tile[d][c + 2]);
        u.z = (int)*reinterpret_cast<const u32*>(&tile[d][c + 4]);
        u.w = (int)*reinterpret_cast<const u32*>(&tile[d][c + 6]);
        *reinterpret_cast<int4*>(dstT + ((long long)(b * Cc + d)) * Nn + n0 + c) = u;
        if (doExp) {
            const unsigned uu[4] = {(unsigned)u.x, (unsigned)u.y, (unsigned)u.z, (unsigned)u.w};
            float ss = 0.f;
#pragma unroll
            for (int j = 0; j < 4; ++j) {
                ss += bf2f((u16)(uu[j] & 0xffff));
                ss += bf2f((u16)(uu[j] >> 16));
            }
            ss += __shfl_xor(ss, 1);
            ss += __shfl_xor(ss, 2);
            ss += __shfl_xor(ss, 4);
            if ((t & 7) == 0) pS[((long long)b * 144 + nc) * Cc + d] = ss;
        }
    }
}

// ---------------- K2b: colS[b][d] = sum over 144 chunks
__global__ __launch_bounds__(256) void k_colcomb(const float* __restrict__ pS,
                                                 float* __restrict__ colS) {
    const int d = threadIdx.x, b = blockIdx.x;
    float s = 0.f;
    for (int c = 0; c < 144; ++c) s += pS[((long long)b * 144 + c) * Cc + d];
    colS[b * Cc + d] = s;
}

// ---------------- K6: bf16 MFMA GEMM (ctx).  C[m][n] = sum_k A[m][k] * Bt[n][k]
// C-store via per-wave LDS patch -> 256-B contiguous store segments.
__global__ __launch_bounds__(256) void k_mm_bf16(const u16* __restrict__ A,
                                                 const u16* __restrict__ Bt,
                                                 float* __restrict__ C,
                                                 int lda, int ldb, int ldc,
                                                 long long sAb, long long sBb, long long sCb,
                                                 int kChunk, long long sCk,
                                                 int tilesN, int kIters) {
    __shared__ alignas(16) unsigned char smemRaw[32768];
    u16* Asm = reinterpret_cast<u16*>(smemRaw);            // 16 KB
    u16* Bsm = reinterpret_cast<u16*>(smemRaw + 16384);    // 16 KB
    float (*patch)[16][68] = reinterpret_cast<float (*)[16][68]>(smemRaw);  // reuse

    const int t = threadIdx.x;
    const int b = blockIdx.z, kc = blockIdx.y;
    const int tm = blockIdx.x / tilesN, tn = blockIdx.x % tilesN;
    const int m0 = tm * 128, n0 = tn * 128;
    const u16* Ag = A + b * sAb + (long long)kc * kChunk;
    const u16* Bg = Bt + b * sBb + (long long)kc * kChunk;
    float* Cg = C + b * sCb + (long long)kc * sCk;

    const int l = t & 63, w = t >> 6;
    const int wr = w >> 1, wc = w & 1;
    const int frow = l & 15, fk = (l >> 4) << 3;

    f32x4 acc[4][4] = {};

    for (int kt = 0; kt < kIters; ++kt) {
        const int k0 = kt * 64;
        int4 av[4], bv[4];
#pragma unroll
        for (int i = 0; i < 4; ++i) {
            const int s = t + 256 * i;
            const int r = s >> 3, c16 = s & 7;
            av[i] = *reinterpret_cast<const int4*>(Ag + (long long)(m0 + r) * lda + k0 + c16 * 8);
            bv[i] = *reinterpret_cast<const int4*>(Bg + (long long)(n0 + r) * ldb + k0 + c16 * 8);
        }
        __syncthreads();
#pragma unroll
        for (int i = 0; i < 4; ++i) {
            const int s = t + 256 * i;
            const int r = s >> 3, c16 = s & 7;
            const int idx = r * 64 + ((c16 * 8) ^ ((r & 7) << 3));
            *reinterpret_cast<int4*>(&Asm[idx]) = av[i];
            *reinterpret_cast<int4*>(&Bsm[idx]) = bv[i];
        }
        __syncthreads();
#pragma unroll
        for (int kf = 0; kf < 2; ++kf) {
            short8 af[4], bf[4];
            const int kk = kf * 32 + fk;
#pragma unroll
            for (int mi = 0; mi < 4; ++mi) {
                const int row = wr * 64 + mi * 16 + frow;
                af[mi] = *reinterpret_cast<const short8*>(&Asm[row * 64 + (kk ^ ((row & 7) << 3))]);
            }
#pragma unroll
            for (int ni = 0; ni < 4; ++ni) {
                const int row = wc * 64 + ni * 16 + frow;
                bf[ni] = *reinterpret_cast<const short8*>(&Bsm[row * 64 + (kk ^ ((row & 7) << 3))]);
            }
#pragma unroll
            for (int mi = 0; mi < 4; ++mi)
#pragma unroll
                for (int ni = 0; ni < 4; ++ni)
                    acc[mi][ni] = __builtin_amdgcn_mfma_f32_16x16x32_bf16(af[mi], bf[ni], acc[mi][ni], 0, 0, 0);
        }
    }

    __syncthreads();   // all waves done reading Asm/Bsm before patch reuse
    const int crow0 = (l >> 4) * 4, ccol = l & 15;
#pragma unroll
    for (int mi = 0; mi < 4; ++mi) {
#pragma unroll
        for (int ni = 0; ni < 4; ++ni)
#pragma unroll
            for (int r_ = 0; r_ < 4; ++r_)
                patch[w][crow0 + r_][ni * 16 + ccol] = acc[mi][ni][r_];
        asm volatile("s_waitcnt lgkmcnt(0)" ::: "memory");
        __builtin_amdgcn_sched_barrier(0);
#pragma unroll
        for (int row = 0; row < 16; ++row)
            Cg[(long long)(m0 + wr * 64 + mi * 16 + row) * ldc + n0 + wc * 64 + l] = patch[w][row][l];
        asm volatile("s_waitcnt lgkmcnt(0)" ::: "memory");
        __builtin_amdgcn_sched_barrier(0);
    }
}

// ---------------- K3b: split-K reduction + 1/colS row scale
__global__ __launch_bounds__(256) void k_ctxred(const float* __restrict__ ctxp,
                                                const float* __restrict__ colS,
                                                float* __restrict__ ctx) {
    const long long i4 = ((long long)blockIdx.x * 256 + threadIdx.x) * 4;
    float4 s = make_float4(0.f, 0.f, 0.f, 0.f);
    for (int kc = 0; kc < KS2; ++kc) {
        const float4 v = *reinterpret_cast<const float4*>(ctxp + (long long)kc * (Bb * Cc * Cc) + i4);
        s.x += v.x; s.y += v.y; s.z += v.z; s.w += v.w;
    }
    const int b = (int)(i4 >> 16);
    const int d = ((int)(i4 >> 8)) & 255;
    const float inv = 1.0f / colS[b * Cc + d];
    s.x *= inv; s.y *= inv; s.z *= inv; s.w *= inv;
    *reinterpret_cast<float4*>(ctx + i4) = s;
}

// ---------------- K4: rank + combined top-k softmax coefficients. block per (b,d) row.
__global__ __launch_bounds__(256) void k_rank(const float* __restrict__ ctx,
                                              const float* __restrict__ aw,
                                              float* __restrict__ Ac) {
    __shared__ float row[256];
    __shared__ float red[256];
    const int d = blockIdx.x, b = blockIdx.y, e = threadIdx.x;
    const float c = ctx[((long long)(b * Cc + d)) * Cc + e];
    row[e] = c;
    __syncthreads();
    int p = 0;
    for (int j = 0; j < 256; ++j) {
        const float cj = row[j];
        p += (cj > c) || (cj == c && j < e);  // stable top_k rank (0-based)
    }
    red[e] = c; __syncthreads();
    for (int s_ = 128; s_; s_ >>= 1) { if (e < s_) red[e] = fmaxf(red[e], red[e + s_]); __syncthreads(); }
    const float m = red[0];
    const float ex = __expf(c - m);
    const int kks[4] = {128, 170, 192, 204};
    float Zv[4];
#pragma unroll
    for (int i = 0; i < 4; ++i) {
        __syncthreads();
        red[e] = (p < kks[i]) ? ex : 0.0f;
        __syncthreads();
        for (int s_ = 128; s_; s_ >>= 1) { if (e < s_) red[e] += red[e + s_]; __syncthreads(); }
        Zv[i] = red[0];
    }
    float wsum = 0.0f;
#pragma unroll
    for (int i = 0; i < 4; ++i)
        if (p < kks[i]) wsum += aw[i] / Zv[i];
    Ac[((long long)(b * Cc + d)) * Cc + e] = ex * wsum;
}

// ---------------- K5: WA[b,o,e] = sum_d W[o,d] * A[b,d,e] -> bf16. grid (32, 8), block 256.
__global__ __launch_bounds__(256) void k_wa(const float* __restrict__ W,
                                            const float* __restrict__ Ac,
                                            u16* __restrict__ WAb16) {
    __shared__ float As[16][64], Bs[16][64];
    const int b = blockIdx.y;
    const int o0 = (blockIdx.x >> 2) * 64, e0 = (blockIdx.x & 3) * 64;
    const int t = threadIdx.x, tx = t & 15, ty = t >> 4;
    const int a_oo = t >> 2, a_k4 = (t & 3) * 4;
    const int b_kk = t >> 4, b_e4 = (t & 15) * 4;
    float acc[4][4] = {{0.f}};
    for (int kd = 0; kd < 256; kd += 16) {
        const float4 wv = *reinterpret_cast<const float4*>(W + (o0 + a_oo) * Cc + kd + a_k4);
        const float4 av = *reinterpret_cast<const float4*>(Ac + ((long long)(b * Cc + kd + b_kk)) * Cc + e0 + b_e4);
        __syncthreads();
        As[a_k4 + 0][a_oo] = wv.x; As[a_k4 + 1][a_oo] = wv.y;
        As[a_k4 + 2][a_oo] = wv.z; As[a_k4 + 3][a_oo] = wv.w;
        *reinterpret_cast<float4*>(&Bs[b_kk][b_e4]) = av;
        __syncthreads();
#pragma unroll
        for (int kk = 0; kk < 16; ++kk) {
            const float4 a4 = *reinterpret_cast<const float4*>(&As[kk][ty * 4]);
            const float4 b4 = *reinterpret_cast<const float4*>(&Bs[kk][tx * 4]);
            const float aa[4] = {a4.x, a4.y, a4.z, a4.w};
            const float bb[4] = {b4.x, b4.y, b4.z, b4.w};
#pragma unroll
            for (int i = 0; i < 4; ++i)
#pragma unroll
                for (int j = 0; j < 4; ++j) acc[i][j] = fmaf(aa[i], bb[j], acc[i][j]);
        }
    }
#pragma unroll
    for (int i = 0; i < 4; ++i) {
        int2 pk;
        pk.x = (int)((unsigned)f2bf(acc[i][0]) | ((unsigned)f2bf(acc[i][1]) << 16));
        pk.y = (int)((unsigned)f2bf(acc[i][2]) | ((unsigned)f2bf(acc[i][3]) << 16));
        *reinterpret_cast<int2*>(WAb16 + ((long long)(b * Oo + o0 + ty * 4 + i)) * Cc + e0 + tx * 4) = pk;
    }
}

// ---------------- K7 v8: fused reprojection GEMM + bias + LN(512) + transposed store.
// Occupancy-first: 8 waves/block, each wave 32n x 64o (acc = 32 AGPR, ~50 arch VGPR)
// -> ~6 waves/SIMD resident to hide load latency. Simple load->MFMA loop (no manual
// pipelining; compiler schedules). grid (288, 1, 8), block 512.
__global__ __launch_bounds__(512, 4) void k_rpln(const u16* __restrict__ Qexp,
                                                 const u16* __restrict__ WAb16,
                                                 const float* __restrict__ rbias,
                                                 const float* __restrict__ nw,
                                                 const float* __restrict__ nb,
                                                 float* __restrict__ out) {
    __shared__ float patch[8][16][36];          // per-wave 16 o x 32 n
    __shared__ float psum[32][8], psq[32][8];
    __shared__ float muA[32], rsA[32];

    const int t = threadIdx.x;
    const int b = blockIdx.z;
    const int nt_ = (blockIdx.x & 7) * 36 + (blockIdx.x >> 3);   // XCD swizzle (288 = 8*36)
    const int n0 = nt_ * 32;
    const int l = t & 63, w = t >> 6;           // 8 waves; wave w owns o = w*64..w*64+63
    const int frow = l & 15, fk = (l >> 4) << 3;
    const int hi = l >> 4;

    f32x4 acc[2][4] = {};

    const u16* Aq = Qexp + ((long long)b * Nn + n0) * Cc;
    const u16* Bw = WAb16 + ((long long)b * Oo + w * 64) * Cc;

    for (int s = 0; s < 8; ++s) {
        const int kk = s * 32 + fk;
        short8 af[2], bf[4];
#pragma unroll
        for (int mi = 0; mi < 2; ++mi)
            af[mi] = __builtin_bit_cast(short8,
                *reinterpret_cast<const int4*>(Aq + (mi * 16 + frow) * Cc + kk));
#pragma unroll
        for (int ni = 0; ni < 4; ++ni)
            bf[ni] = __builtin_bit_cast(short8,
                *reinterpret_cast<const int4*>(Bw + (ni * 16 + frow) * Cc + kk));
#pragma unroll
        for (int mi = 0; mi < 2; ++mi)
#pragma unroll
            for (int ni = 0; ni < 4; ++ni)
                acc[mi][ni] = __builtin_amdgcn_mfma_f32_16x16x32_bf16(af[mi], bf[ni], acc[mi][ni], 0, 0, 0);
    }

    // ---- epilogue: +bias
#pragma unroll
    for (int ni = 0; ni < 4; ++ni) {
        const float bb = rbias[w * 64 + ni * 16 + frow];
#pragma unroll
        for (int mi = 0; mi < 2; ++mi)
#pragma unroll
            for (int r_ = 0; r_ < 4; ++r_) acc[mi][ni][r_] += bb;
    }
    // per-row LN partials over this wave's 64 cols
#pragma unroll
    for (int mi = 0; mi < 2; ++mi)
#pragma unroll
        for (int r_ = 0; r_ < 4; ++r_) {
            float s = 0.f, q = 0.f;
#pragma unroll
            for (int ni = 0; ni < 4; ++ni) { const float v = acc[mi][ni][r_]; s += v; q += v * v; }
#pragma unroll
            for (int m = 8; m; m >>= 1) { s += __shfl_xor(s, m); q += __shfl_xor(q, m); }
            if (frow == 0) {
                const int row = mi * 16 + hi * 4 + r_;
                psum[row][w] = s; psq[row][w] = q;
            }
        }
    __syncthreads();
    if (t < 32) {
        float s = 0.f, q = 0.f;
#pragma unroll
        for (int i = 0; i < 8; ++i) { s += psum[t][i]; q += psq[t][i]; }
        const float m = s * (1.0f / Oo);
        muA[t] = m;
        rsA[t] = rsqrtf(q * (1.0f / Oo) - m * m + LN_EPS);
    }
    __syncthreads();

    float nwv[4], nbv[4];
#pragma unroll
    for (int ni = 0; ni < 4; ++ni) {
        const int o = w * 64 + ni * 16 + frow;
        nwv[ni] = nw[o]; nbv[ni] = nb[o];
    }

    // per ni: wave-private 16o x 32n patch -> float4 stores (128-B segments).
#pragma unroll
    for (int ni = 0; ni < 4; ++ni) {
#pragma unroll
        for (int mi = 0; mi < 2; ++mi)
#pragma unroll
            for (int r_ = 0; r_ < 4; ++r_) {
                const int nl = mi * 16 + hi * 4 + r_;              // 0..31
                patch[w][frow][nl] = (acc[mi][ni][r_] - muA[nl]) * rsA[nl] * nwv[ni] + nbv[ni];
            }
        asm volatile("s_waitcnt lgkmcnt(0)" ::: "memory");
        __builtin_amdgcn_sched_barrier(0);
#pragma unroll
        for (int p = 0; p < 2; ++p) {
            const int o_loc = p * 8 + (l >> 3);                    // 0..15
            const int colf4 = l & 7;                               // 0..7
            const float4 v = *reinterpret_cast<const float4*>(&patch[w][o_loc][colf4 * 4]);
            const int o_g = w * 64 + ni * 16 + o_loc;
            *reinterpret_cast<float4*>(&out[((long long)(b * Oo + o_g)) * Nn + n0 + colf4 * 4]) = v;
        }
        asm volatile("s_waitcnt lgkmcnt(0)" ::: "memory");
        __builtin_amdgcn_sched_barrier(0);
    }
}

extern "C" void kernel_launch(void* const* d_in, const int* in_sizes, int n_in,
                              void* d_out, int out_size, void* d_ws, size_t ws_size,
                              hipStream_t stream) {
    (void)in_sizes; (void)n_in; (void)out_size; (void)ws_size;
    const float* x1    = (const float*)d_in[0];
    const float* x2    = (const float*)d_in[1];
    const float* n1w   = (const float*)d_in[2];
    const float* n1b   = (const float*)d_in[3];
    const float* rw    = (const float*)d_in[4];
    const float* rbias = (const float*)d_in[5];
    const float* n2w   = (const float*)d_in[6];
    const float* n2b   = (const float*)d_in[7];
    const float* aw    = (const float*)d_in[8];
    float* out = (float*)d_out;

    // d_out doubles as scratch for KexpT/VT (dead before k_rpln's final overwrite).
    u16* KexpT = (u16*)d_out;
    u16* VT    = KexpT + (size_t)Bb * Nn * Cc;

    float* ws = (float*)d_ws;
    size_t off = 0;
    u16*   Qexp   = (u16*)(ws + off); off += (size_t)Bb * Nn * Cc / 2;
    float* ctxp   = ws + off; off += (size_t)KS2 * Bb * Cc * Cc;
    float* ctx    = ws + off; off += (size_t)Bb * Cc * Cc;
    float* Ac     = ws + off; off += (size_t)Bb * Cc * Cc;
    u16*   WAb16  = (u16*)(ws + off); off += (size_t)Bb * Oo * Cc / 2;
    float* pS     = ws + off; off += (size_t)Bb * 144 * Cc;
    float* colS   = ws + off; off += (size_t)Bb * Cc;

    k_pre<<<dim3(144, 1, Bb), 512, 0, stream>>>(x2, n1w, n1b, KexpT, Qexp, pS, 1);
    k_pre<<<dim3(144, 1, Bb), 512, 0, stream>>>(x1, n1w, n1b, VT, Qexp, pS, 0);
    k_colcomb<<<dim3(Bb), 256, 0, stream>>>(pS, colS);
    k_mm_bf16<<<dim3(4, KS2, Bb), 256, 0, stream>>>(
        KexpT, VT, ctxp,
        Nn, Nn, Cc,
        (long long)Cc * Nn, (long long)Cc * Nn, (long long)Cc * Cc,
        Nn / KS2, (long long)Bb * Cc * Cc,
        Cc / 128, (Nn / KS2) / 64);
    k_ctxred<<<dim3(512), 256, 0, stream>>>(ctxp, colS, ctx);
    k_rank<<<dim3(Cc, Bb), 256, 0, stream>>>(ctx, aw, Ac);
    k_wa<<<dim3(32, Bb), 256, 0, stream>>>(rw, Ac, WAb16);
    k_rpln<<<dim3(288, 1, Bb), 512, 0, stream>>>(Qexp, WAb16, rbias, n2w, n2b, out);
}

// Round 15
// 258.652 us; speedup vs baseline: 1.1017x; 1.1017x over previous
//
#include <hip/hip_runtime.h>
#include <math.h>

typedef __attribute__((ext_vector_type(8))) short short8;
typedef __attribute__((ext_vector_type(4))) float f32x4;
typedef unsigned short u16;
typedef unsigned int u32;

constexpr int Bb = 8;
constexpr int Nn = 9216;   // 96*96
constexpr int Cc = 256;    // = D
constexpr int Oo = 512;    // 2C
constexpr float LN_EPS = 1e-5f;
constexpr int KS2 = 8;     // ctx GEMM split-K chunks (9216 = 8*1152)

static __device__ __forceinline__ u16 f2bf(float f) {
    unsigned u = __builtin_bit_cast(unsigned, f);
    u += 0x7fffu + ((u >> 16) & 1u);   // RNE
    return (u16)(u >> 16);
}
static __device__ __forceinline__ float bf2f(u16 u) {
    return __builtin_bit_cast(float, (unsigned)u << 16);
}

// ---------------- K_pre v3: fused per-input pass (512 threads, 64n x 256d per block).
__global__ __launch_bounds__(512, 2) void k_pre(const float* __restrict__ src,
                                                const float* __restrict__ lnw,
                                                const float* __restrict__ lnb,
                                                u16* __restrict__ dstT,
                                                u16* __restrict__ Qexp,
                                                float* __restrict__ pS,
                                                int doExp) {
    __shared__ u16 tile[256][66];    // [d][n], pad 66 (132 B rows)
    __shared__ float wsh[256], bsh[256];
    const int b = blockIdx.z;
    const int nc = (blockIdx.x & 7) * 18 + (blockIdx.x >> 3);   // XCD swizzle (144 = 8*18)
    const int n0 = nc * 64;
    const int t = threadIdx.x;
    if (t < 256) { wsh[t] = lnw[t]; bsh[t] = lnb[t]; }
    __syncthreads();

    const int r = t >> 3;            // 0..63
    const int g = t & 7;             // 0..7
    const long long row = (long long)b * Nn + n0 + r;
    const float* rowp = src + row * Cc;

    float4 v[8];
#pragma unroll
    for (int i = 0; i < 8; ++i)
        v[i] = *reinterpret_cast<const float4*>(rowp + g * 4 + i * 32);

    float s = 0.f, q = 0.f;
#pragma unroll
    for (int i = 0; i < 8; ++i) {
        s += v[i].x + v[i].y + v[i].z + v[i].w;
        q += v[i].x * v[i].x + v[i].y * v[i].y + v[i].z * v[i].z + v[i].w * v[i].w;
    }
    s += __shfl_xor(s, 1); s += __shfl_xor(s, 2); s += __shfl_xor(s, 4);
    q += __shfl_xor(q, 1); q += __shfl_xor(q, 2); q += __shfl_xor(q, 4);
    const float mu = s * (1.0f / Cc);
    const float rstd = rsqrtf(q * (1.0f / Cc) - mu * mu + LN_EPS);

    float se = 0.f;
#pragma unroll
    for (int i = 0; i < 8; ++i) {
        const int d = g * 4 + i * 32;
        const float4 w4 = *reinterpret_cast<const float4*>(&wsh[d]);
        const float4 b4 = *reinterpret_cast<const float4*>(&bsh[d]);
        v[i].x = (v[i].x - mu) * rstd * w4.x + b4.x;
        v[i].y = (v[i].y - mu) * rstd * w4.y + b4.y;
        v[i].z = (v[i].z - mu) * rstd * w4.z + b4.z;
        v[i].w = (v[i].w - mu) * rstd * w4.w + b4.w;
        if (doExp) {
            v[i].x = __expf(v[i].x); v[i].y = __expf(v[i].y);
            v[i].z = __expf(v[i].z); v[i].w = __expf(v[i].w);
            se += v[i].x + v[i].y + v[i].z + v[i].w;
        }
        tile[d + 0][r] = f2bf(v[i].x);
        tile[d + 1][r] = f2bf(v[i].y);
        tile[d + 2][r] = f2bf(v[i].z);
        tile[d + 3][r] = f2bf(v[i].w);
    }

    if (doExp) {
        se += __shfl_xor(se, 1); se += __shfl_xor(se, 2); se += __shfl_xor(se, 4);
        const float inv = 1.0f / se;
#pragma unroll
        for (int i = 0; i < 8; ++i) {
            const int d = g * 4 + i * 32;
            int2 pk;
            pk.x = (int)((unsigned)f2bf(v[i].x * inv) | ((unsigned)f2bf(v[i].y * inv) << 16));
            pk.y = (int)((unsigned)f2bf(v[i].z * inv) | ((unsigned)f2bf(v[i].w * inv) << 16));
            *reinterpret_cast<int2*>(Qexp + row * Cc + d) = pk;
        }
    }
    __syncthreads();

    // transposed global write (4x b32 reads: 132-B rows keep 4-B alignment)
#pragma unroll
    for (int p = 0; p < 4; ++p) {
        const int d = p * 64 + (t >> 3);
        const int c = (t & 7) * 8;
        int4 u;
        u.x = (int)*reinterpret_cast<const u32*>(&tile[d][c + 0]);
        u.y = (int)*reinterpret_cast<const u32*>(&tile[d][c + 2]);
        u.z = (int)*reinterpret_cast<const u32*>(&tile[d][c + 4]);
        u.w = (int)*reinterpret_cast<const u32*>(&tile[d][c + 6]);
        *reinterpret_cast<int4*>(dstT + ((long long)(b * Cc + d)) * Nn + n0 + c) = u;
        if (doExp) {
            const unsigned uu[4] = {(unsigned)u.x, (unsigned)u.y, (unsigned)u.z, (unsigned)u.w};
            float ss = 0.f;
#pragma unroll
            for (int j = 0; j < 4; ++j) {
                ss += bf2f((u16)(uu[j] & 0xffff));
                ss += bf2f((u16)(uu[j] >> 16));
            }
            ss += __shfl_xor(ss, 1);
            ss += __shfl_xor(ss, 2);
            ss += __shfl_xor(ss, 4);
            if ((t & 7) == 0) pS[((long long)b * 144 + nc) * Cc + d] = ss;
        }
    }
}

// ---------------- K2b: colS[b][d] = sum over 144 chunks
__global__ __launch_bounds__(256) void k_colcomb(const float* __restrict__ pS,
                                                 float* __restrict__ colS) {
    const int d = threadIdx.x, b = blockIdx.x;
    float s = 0.f;
    for (int c = 0; c < 144; ++c) s += pS[((long long)b * 144 + c) * Cc + d];
    colS[b * Cc + d] = s;
}

// ---------------- K6: bf16 MFMA GEMM (ctx).  C[m][n] = sum_k A[m][k] * Bt[n][k]
// C-store via per-wave LDS patch -> 256-B contiguous store segments.
__global__ __launch_bounds__(256) void k_mm_bf16(const u16* __restrict__ A,
                                                 const u16* __restrict__ Bt,
                                                 float* __restrict__ C,
                                                 int lda, int ldb, int ldc,
                                                 long long sAb, long long sBb, long long sCb,
                                                 int kChunk, long long sCk,
                                                 int tilesN, int kIters) {
    __shared__ alignas(16) unsigned char smemRaw[32768];
    u16* Asm = reinterpret_cast<u16*>(smemRaw);            // 16 KB
    u16* Bsm = reinterpret_cast<u16*>(smemRaw + 16384);    // 16 KB
    float (*patch)[16][68] = reinterpret_cast<float (*)[16][68]>(smemRaw);  // reuse

    const int t = threadIdx.x;
    const int b = blockIdx.z, kc = blockIdx.y;
    const int tm = blockIdx.x / tilesN, tn = blockIdx.x % tilesN;
    const int m0 = tm * 128, n0 = tn * 128;
    const u16* Ag = A + b * sAb + (long long)kc * kChunk;
    const u16* Bg = Bt + b * sBb + (long long)kc * kChunk;
    float* Cg = C + b * sCb + (long long)kc * sCk;

    const int l = t & 63, w = t >> 6;
    const int wr = w >> 1, wc = w & 1;
    const int frow = l & 15, fk = (l >> 4) << 3;

    f32x4 acc[4][4] = {};

    for (int kt = 0; kt < kIters; ++kt) {
        const int k0 = kt * 64;
        int4 av[4], bv[4];
#pragma unroll
        for (int i = 0; i < 4; ++i) {
            const int s = t + 256 * i;
            const int r = s >> 3, c16 = s & 7;
            av[i] = *reinterpret_cast<const int4*>(Ag + (long long)(m0 + r) * lda + k0 + c16 * 8);
            bv[i] = *reinterpret_cast<const int4*>(Bg + (long long)(n0 + r) * ldb + k0 + c16 * 8);
        }
        __syncthreads();
#pragma unroll
        for (int i = 0; i < 4; ++i) {
            const int s = t + 256 * i;
            const int r = s >> 3, c16 = s & 7;
            const int idx = r * 64 + ((c16 * 8) ^ ((r & 7) << 3));
            *reinterpret_cast<int4*>(&Asm[idx]) = av[i];
            *reinterpret_cast<int4*>(&Bsm[idx]) = bv[i];
        }
        __syncthreads();
#pragma unroll
        for (int kf = 0; kf < 2; ++kf) {
            short8 af[4], bf[4];
            const int kk = kf * 32 + fk;
#pragma unroll
            for (int mi = 0; mi < 4; ++mi) {
                const int row = wr * 64 + mi * 16 + frow;
                af[mi] = *reinterpret_cast<const short8*>(&Asm[row * 64 + (kk ^ ((row & 7) << 3))]);
            }
#pragma unroll
            for (int ni = 0; ni < 4; ++ni) {
                const int row = wc * 64 + ni * 16 + frow;
                bf[ni] = *reinterpret_cast<const short8*>(&Bsm[row * 64 + (kk ^ ((row & 7) << 3))]);
            }
#pragma unroll
            for (int mi = 0; mi < 4; ++mi)
#pragma unroll
                for (int ni = 0; ni < 4; ++ni)
                    acc[mi][ni] = __builtin_amdgcn_mfma_f32_16x16x32_bf16(af[mi], bf[ni], acc[mi][ni], 0, 0, 0);
        }
    }

    __syncthreads();   // all waves done reading Asm/Bsm before patch reuse
    const int crow0 = (l >> 4) * 4, ccol = l & 15;
#pragma unroll
    for (int mi = 0; mi < 4; ++mi) {
#pragma unroll
        for (int ni = 0; ni < 4; ++ni)
#pragma unroll
            for (int r_ = 0; r_ < 4; ++r_)
                patch[w][crow0 + r_][ni * 16 + ccol] = acc[mi][ni][r_];
        asm volatile("s_waitcnt lgkmcnt(0)" ::: "memory");
        __builtin_amdgcn_sched_barrier(0);
#pragma unroll
        for (int row = 0; row < 16; ++row)
            Cg[(long long)(m0 + wr * 64 + mi * 16 + row) * ldc + n0 + wc * 64 + l] = patch[w][row][l];
        asm volatile("s_waitcnt lgkmcnt(0)" ::: "memory");
        __builtin_amdgcn_sched_barrier(0);
    }
}

// ---------------- K3b: split-K reduction + 1/colS row scale
__global__ __launch_bounds__(256) void k_ctxred(const float* __restrict__ ctxp,
                                                const float* __restrict__ colS,
                                                float* __restrict__ ctx) {
    const long long i4 = ((long long)blockIdx.x * 256 + threadIdx.x) * 4;
    float4 s = make_float4(0.f, 0.f, 0.f, 0.f);
    for (int kc = 0; kc < KS2; ++kc) {
        const float4 v = *reinterpret_cast<const float4*>(ctxp + (long long)kc * (Bb * Cc * Cc) + i4);
        s.x += v.x; s.y += v.y; s.z += v.z; s.w += v.w;
    }
    const int b = (int)(i4 >> 16);
    const int d = ((int)(i4 >> 8)) & 255;
    const float inv = 1.0f / colS[b * Cc + d];
    s.x *= inv; s.y *= inv; s.z *= inv; s.w *= inv;
    *reinterpret_cast<float4*>(ctx + i4) = s;
}

// ---------------- K4: rank + combined top-k softmax coefficients. block per (b,d) row.
__global__ __launch_bounds__(256) void k_rank(const float* __restrict__ ctx,
                                              const float* __restrict__ aw,
                                              float* __restrict__ Ac) {
    __shared__ float row[256];
    __shared__ float red[256];
    const int d = blockIdx.x, b = blockIdx.y, e = threadIdx.x;
    const float c = ctx[((long long)(b * Cc + d)) * Cc + e];
    row[e] = c;
    __syncthreads();
    int p = 0;
    for (int j = 0; j < 256; ++j) {
        const float cj = row[j];
        p += (cj > c) || (cj == c && j < e);  // stable top_k rank (0-based)
    }
    red[e] = c; __syncthreads();
    for (int s_ = 128; s_; s_ >>= 1) { if (e < s_) red[e] = fmaxf(red[e], red[e + s_]); __syncthreads(); }
    const float m = red[0];
    const float ex = __expf(c - m);
    const int kks[4] = {128, 170, 192, 204};
    float Zv[4];
#pragma unroll
    for (int i = 0; i < 4; ++i) {
        __syncthreads();
        red[e] = (p < kks[i]) ? ex : 0.0f;
        __syncthreads();
        for (int s_ = 128; s_; s_ >>= 1) { if (e < s_) red[e] += red[e + s_]; __syncthreads(); }
        Zv[i] = red[0];
    }
    float wsum = 0.0f;
#pragma unroll
    for (int i = 0; i < 4; ++i)
        if (p < kks[i]) wsum += aw[i] / Zv[i];
    Ac[((long long)(b * Cc + d)) * Cc + e] = ex * wsum;
}

// ---------------- K5: WA[b,o,e] = sum_d W[o,d] * A[b,d,e] -> bf16. grid (32, 8), block 256.
__global__ __launch_bounds__(256) void k_wa(const float* __restrict__ W,
                                            const float* __restrict__ Ac,
                                            u16* __restrict__ WAb16) {
    __shared__ float As[16][64], Bs[16][64];
    const int b = blockIdx.y;
    const int o0 = (blockIdx.x >> 2) * 64, e0 = (blockIdx.x & 3) * 64;
    const int t = threadIdx.x, tx = t & 15, ty = t >> 4;
    const int a_oo = t >> 2, a_k4 = (t & 3) * 4;
    const int b_kk = t >> 4, b_e4 = (t & 15) * 4;
    float acc[4][4] = {{0.f}};
    for (int kd = 0; kd < 256; kd += 16) {
        const float4 wv = *reinterpret_cast<const float4*>(W + (o0 + a_oo) * Cc + kd + a_k4);
        const float4 av = *reinterpret_cast<const float4*>(Ac + ((long long)(b * Cc + kd + b_kk)) * Cc + e0 + b_e4);
        __syncthreads();
        As[a_k4 + 0][a_oo] = wv.x; As[a_k4 + 1][a_oo] = wv.y;
        As[a_k4 + 2][a_oo] = wv.z; As[a_k4 + 3][a_oo] = wv.w;
        *reinterpret_cast<float4*>(&Bs[b_kk][b_e4]) = av;
        __syncthreads();
#pragma unroll
        for (int kk = 0; kk < 16; ++kk) {
            const float4 a4 = *reinterpret_cast<const float4*>(&As[kk][ty * 4]);
            const float4 b4 = *reinterpret_cast<const float4*>(&Bs[kk][tx * 4]);
            const float aa[4] = {a4.x, a4.y, a4.z, a4.w};
            const float bb[4] = {b4.x, b4.y, b4.z, b4.w};
#pragma unroll
            for (int i = 0; i < 4; ++i)
#pragma unroll
                for (int j = 0; j < 4; ++j) acc[i][j] = fmaf(aa[i], bb[j], acc[i][j]);
        }
    }
#pragma unroll
    for (int i = 0; i < 4; ++i) {
        int2 pk;
        pk.x = (int)((unsigned)f2bf(acc[i][0]) | ((unsigned)f2bf(acc[i][1]) << 16));
        pk.y = (int)((unsigned)f2bf(acc[i][2]) | ((unsigned)f2bf(acc[i][3]) << 16));
        *reinterpret_cast<int2*>(WAb16 + ((long long)(b * Oo + o0 + ty * 4 + i)) * Cc + e0 + tx * 4) = pk;
    }
}

// ---------------- K7 (R8/R12 proven config + nontemporal out stores):
// fused reprojection GEMM + bias + LN(512) + transposed store.
// All 16 A-fragments preloaded up front; B (L2-resident) 1-step prefetch.
// grid (288, 1, 8), block 256 (4 waves x 128 o), XCD-swizzled n-tiles.
__global__ __launch_bounds__(256, 3) void k_rpln(const u16* __restrict__ Qexp,
                                                 const u16* __restrict__ WAb16,
                                                 const float* __restrict__ rbias,
                                                 const float* __restrict__ nw,
                                                 const float* __restrict__ nb,
                                                 float* __restrict__ out) {
    __shared__ float patch[4][16][36];          // per-wave 16 o x 32 n
    __shared__ float psum[32][4], psq[32][4];
    __shared__ float muA[32], rsA[32];

    const int t = threadIdx.x;
    const int b = blockIdx.z;
    const int nt_ = (blockIdx.x & 7) * 36 + (blockIdx.x >> 3);   // XCD swizzle (288 = 8*36)
    const int n0 = nt_ * 32;
    const int l = t & 63, w = t >> 6;           // wave w owns o = w*128..
    const int frow = l & 15, fk = (l >> 4) << 3;
    const int hi = l >> 4;

    f32x4 acc[2][8] = {};

    const u16* Aq = Qexp + ((long long)b * Nn + n0) * Cc;
    const u16* Bw = WAb16 + ((long long)b * Oo + w * 128) * Cc;

    // preload ALL A fragments: 2 n-halves x 8 K-steps
    int4 aF[2][8];
#pragma unroll
    for (int mi = 0; mi < 2; ++mi)
#pragma unroll
        for (int s = 0; s < 8; ++s)
            aF[mi][s] = *reinterpret_cast<const int4*>(Aq + (mi * 16 + frow) * Cc + s * 32 + fk);

    int4 bC[8], bN[8];
#pragma unroll
    for (int ni = 0; ni < 8; ++ni)
        bC[ni] = *reinterpret_cast<const int4*>(Bw + (ni * 16 + frow) * Cc + fk);

#pragma unroll
    for (int s = 0; s < 8; ++s) {
        if (s < 7) {
            const int kk = (s + 1) * 32 + fk;
#pragma unroll
            for (int ni = 0; ni < 8; ++ni)
                bN[ni] = *reinterpret_cast<const int4*>(Bw + (ni * 16 + frow) * Cc + kk);
        }
#pragma unroll
        for (int mi = 0; mi < 2; ++mi)
#pragma unroll
            for (int ni = 0; ni < 8; ++ni)
                acc[mi][ni] = __builtin_amdgcn_mfma_f32_16x16x32_bf16(
                    __builtin_bit_cast(short8, aF[mi][s]), __builtin_bit_cast(short8, bC[ni]),
                    acc[mi][ni], 0, 0, 0);
        if (s < 7) {
#pragma unroll
            for (int ni = 0; ni < 8; ++ni) bC[ni] = bN[ni];
        }
    }

    // ---- epilogue: +bias
#pragma unroll
    for (int ni = 0; ni < 8; ++ni) {
        const float bb = rbias[w * 128 + ni * 16 + frow];
#pragma unroll
        for (int mi = 0; mi < 2; ++mi)
#pragma unroll
            for (int r_ = 0; r_ < 4; ++r_) acc[mi][ni][r_] += bb;
    }
    // per-row LN partials over this wave's 128 cols
#pragma unroll
    for (int mi = 0; mi < 2; ++mi)
#pragma unroll
        for (int r_ = 0; r_ < 4; ++r_) {
            float s = 0.f, q = 0.f;
#pragma unroll
            for (int ni = 0; ni < 8; ++ni) { const float v = acc[mi][ni][r_]; s += v; q += v * v; }
#pragma unroll
            for (int m = 8; m; m >>= 1) { s += __shfl_xor(s, m); q += __shfl_xor(q, m); }
            if (frow == 0) {
                const int row = mi * 16 + hi * 4 + r_;
                psum[row][w] = s; psq[row][w] = q;
            }
        }
    __syncthreads();
    if (t < 32) {
        const float s = psum[t][0] + psum[t][1] + psum[t][2] + psum[t][3];
        const float q = psq[t][0] + psq[t][1] + psq[t][2] + psq[t][3];
        const float m = s * (1.0f / Oo);
        muA[t] = m;
        rsA[t] = rsqrtf(q * (1.0f / Oo) - m * m + LN_EPS);
    }
    __syncthreads();

    float nwv[8], nbv[8];
#pragma unroll
    for (int ni = 0; ni < 8; ++ni) {
        const int o = w * 128 + ni * 16 + frow;
        nwv[ni] = nw[o]; nbv[ni] = nb[o];
    }

    // per ni: wave-private 16o x 32n patch -> nontemporal f32x4 stores (out never re-read).
#pragma unroll
    for (int ni = 0; ni < 8; ++ni) {
#pragma unroll
        for (int mi = 0; mi < 2; ++mi)
#pragma unroll
            for (int r_ = 0; r_ < 4; ++r_) {
                const int nl = mi * 16 + hi * 4 + r_;              // 0..31
                patch[w][frow][nl] = (acc[mi][ni][r_] - muA[nl]) * rsA[nl] * nwv[ni] + nbv[ni];
            }
        asm volatile("s_waitcnt lgkmcnt(0)" ::: "memory");
        __builtin_amdgcn_sched_barrier(0);
#pragma unroll
        for (int p = 0; p < 2; ++p) {
            const int o_loc = p * 8 + (l >> 3);                    // 0..15
            const int colf4 = l & 7;                               // 0..7
            const f32x4 v = *reinterpret_cast<const f32x4*>(&patch[w][o_loc][colf4 * 4]);
            const int o_g = w * 128 + ni * 16 + o_loc;
            __builtin_nontemporal_store(v,
                reinterpret_cast<f32x4*>(&out[((long long)(b * Oo + o_g)) * Nn + n0 + colf4 * 4]));
        }
        asm volatile("s_waitcnt lgkmcnt(0)" ::: "memory");
        __builtin_amdgcn_sched_barrier(0);
    }
}

extern "C" void kernel_launch(void* const* d_in, const int* in_sizes, int n_in,
                              void* d_out, int out_size, void* d_ws, size_t ws_size,
                              hipStream_t stream) {
    (void)in_sizes; (void)n_in; (void)out_size; (void)ws_size;
    const float* x1    = (const float*)d_in[0];
    const float* x2    = (const float*)d_in[1];
    const float* n1w   = (const float*)d_in[2];
    const float* n1b   = (const float*)d_in[3];
    const float* rw    = (const float*)d_in[4];
    const float* rbias = (const float*)d_in[5];
    const float* n2w   = (const float*)d_in[6];
    const float* n2b   = (const float*)d_in[7];
    const float* aw    = (const float*)d_in[8];
    float* out = (float*)d_out;

    // d_out doubles as scratch for KexpT/VT (dead before k_rpln's final overwrite).
    u16* KexpT = (u16*)d_out;
    u16* VT    = KexpT + (size_t)Bb * Nn * Cc;

    float* ws = (float*)d_ws;
    size_t off = 0;
    u16*   Qexp   = (u16*)(ws + off); off += (size_t)Bb * Nn * Cc / 2;
    float* ctxp   = ws + off; off += (size_t)KS2 * Bb * Cc * Cc;
    float* ctx    = ws + off; off += (size_t)Bb * Cc * Cc;
    float* Ac     = ws + off; off += (size_t)Bb * Cc * Cc;
    u16*   WAb16  = (u16*)(ws + off); off += (size_t)Bb * Oo * Cc / 2;
    float* pS     = ws + off; off += (size_t)Bb * 144 * Cc;
    float* colS   = ws + off; off += (size_t)Bb * Cc;

    k_pre<<<dim3(144, 1, Bb), 512, 0, stream>>>(x2, n1w, n1b, KexpT, Qexp, pS, 1);
    k_pre<<<dim3(144, 1, Bb), 512, 0, stream>>>(x1, n1w, n1b, VT, Qexp, pS, 0);
    k_colcomb<<<dim3(Bb), 256, 0, stream>>>(pS, colS);
    k_mm_bf16<<<dim3(4, KS2, Bb), 256, 0, stream>>>(
        KexpT, VT, ctxp,
        Nn, Nn, Cc,
        (long long)Cc * Nn, (long long)Cc * Nn, (long long)Cc * Cc,
        Nn / KS2, (long long)Bb * Cc * Cc,
        Cc / 128, (Nn / KS2) / 64);
    k_ctxred<<<dim3(512), 256, 0, stream>>>(ctxp, colS, ctx);
    k_rank<<<dim3(Cc, Bb), 256, 0, stream>>>(ctx, aw, Ac);
    k_wa<<<dim3(32, Bb), 256, 0, stream>>>(rw, Ac, WAb16);
    k_rpln<<<dim3(288, 1, Bb), 256, 0, stream>>>(Qexp, WAb16, rbias, n2w, n2b, out);
}

// Round 16
// 229.696 us; speedup vs baseline: 1.2406x; 1.1261x over previous
//
#include <hip/hip_runtime.h>
#include <math.h>

typedef __attribute__((ext_vector_type(8))) short short8;
typedef __attribute__((ext_vector_type(4))) float f32x4;
typedef unsigned short u16;
typedef unsigned int u32;

constexpr int Bb = 8;
constexpr int Nn = 9216;   // 96*96
constexpr int Cc = 256;    // = D
constexpr int Oo = 512;    // 2C
constexpr float LN_EPS = 1e-5f;
constexpr int KS2 = 8;     // ctx GEMM split-K chunks (9216 = 8*1152)

static __device__ __forceinline__ u16 f2bf(float f) {
    unsigned u = __builtin_bit_cast(unsigned, f);
    u += 0x7fffu + ((u >> 16) & 1u);   // RNE
    return (u16)(u >> 16);
}
static __device__ __forceinline__ float bf2f(u16 u) {
    return __builtin_bit_cast(float, (unsigned)u << 16);
}

// ---------------- K_pre v4: fused per-input pass (512 threads, 64n x 256d per block).
// NO transposes: writes row-major bf16 (exp'd if doExp). doExp also writes rowsum[n]
// and pS column partials (shuffle + cross-wave LDS reduce). All global writes contiguous.
__global__ __launch_bounds__(512, 2) void k_pre(const float* __restrict__ src,
                                                const float* __restrict__ lnw,
                                                const float* __restrict__ lnb,
                                                u16* __restrict__ dst,
                                                float* __restrict__ rowsum,
                                                float* __restrict__ pS,
                                                int doExp) {
    __shared__ float wsh[256], bsh[256];
    __shared__ float wred[8][256];
    const int b = blockIdx.z;
    const int nc = (blockIdx.x & 7) * 18 + (blockIdx.x >> 3);   // XCD swizzle (144 = 8*18)
    const int n0 = nc * 64;
    const int t = threadIdx.x;
    if (t < 256) { wsh[t] = lnw[t]; bsh[t] = lnb[t]; }
    __syncthreads();

    const int r = t >> 3;            // 0..63
    const int g = t & 7;             // 0..7
    const int wv = t >> 6;           // wave 0..7
    const long long row = (long long)b * Nn + n0 + r;
    const float* rowp = src + row * Cc;

    float4 v[8];
#pragma unroll
    for (int i = 0; i < 8; ++i)
        v[i] = *reinterpret_cast<const float4*>(rowp + g * 4 + i * 32);

    float s = 0.f, q = 0.f;
#pragma unroll
    for (int i = 0; i < 8; ++i) {
        s += v[i].x + v[i].y + v[i].z + v[i].w;
        q += v[i].x * v[i].x + v[i].y * v[i].y + v[i].z * v[i].z + v[i].w * v[i].w;
    }
    s += __shfl_xor(s, 1); s += __shfl_xor(s, 2); s += __shfl_xor(s, 4);
    q += __shfl_xor(q, 1); q += __shfl_xor(q, 2); q += __shfl_xor(q, 4);
    const float mu = s * (1.0f / Cc);
    const float rstd = rsqrtf(q * (1.0f / Cc) - mu * mu + LN_EPS);

    float se = 0.f;
    u16 h[8][4];
#pragma unroll
    for (int i = 0; i < 8; ++i) {
        const int d = g * 4 + i * 32;
        const float4 w4 = *reinterpret_cast<const float4*>(&wsh[d]);
        const float4 b4 = *reinterpret_cast<const float4*>(&bsh[d]);
        v[i].x = (v[i].x - mu) * rstd * w4.x + b4.x;
        v[i].y = (v[i].y - mu) * rstd * w4.y + b4.y;
        v[i].z = (v[i].z - mu) * rstd * w4.z + b4.z;
        v[i].w = (v[i].w - mu) * rstd * w4.w + b4.w;
        if (doExp) {
            v[i].x = __expf(v[i].x); v[i].y = __expf(v[i].y);
            v[i].z = __expf(v[i].z); v[i].w = __expf(v[i].w);
            se += v[i].x + v[i].y + v[i].z + v[i].w;
        }
        h[i][0] = f2bf(v[i].x); h[i][1] = f2bf(v[i].y);
        h[i][2] = f2bf(v[i].z); h[i][3] = f2bf(v[i].w);
        int2 pk;
        pk.x = (int)((unsigned)h[i][0] | ((unsigned)h[i][1] << 16));
        pk.y = (int)((unsigned)h[i][2] | ((unsigned)h[i][3] << 16));
        *reinterpret_cast<int2*>(dst + row * Cc + d) = pk;
    }

    if (doExp) {
        se += __shfl_xor(se, 1); se += __shfl_xor(se, 2); se += __shfl_xor(se, 4);
        if (g == 0) rowsum[row] = se;
        // column partials: sum bf16-rounded values over the block's 64 n-rows.
#pragma unroll
        for (int i = 0; i < 8; ++i) {
            float c0 = bf2f(h[i][0]), c1 = bf2f(h[i][1]);
            float c2 = bf2f(h[i][2]), c3 = bf2f(h[i][3]);
#pragma unroll
            for (int m = 8; m <= 32; m <<= 1) {
                c0 += __shfl_xor(c0, m); c1 += __shfl_xor(c1, m);
                c2 += __shfl_xor(c2, m); c3 += __shfl_xor(c3, m);
            }
            if ((t & 63) < 8) {          // lane == g: holds wave-partial
                const int d = g * 4 + i * 32;
                wred[wv][d + 0] = c0; wred[wv][d + 1] = c1;
                wred[wv][d + 2] = c2; wred[wv][d + 3] = c3;
            }
        }
        __syncthreads();
        if (t < 256) {
            float ss = 0.f;
#pragma unroll
            for (int i = 0; i < 8; ++i) ss += wred[i][t];
            pS[((long long)b * 144 + nc) * Cc + t] = ss;
        }
    }
}

// ---------------- K2b: colS[b][d] = sum over 144 chunks
__global__ __launch_bounds__(256) void k_colcomb(const float* __restrict__ pS,
                                                 float* __restrict__ colS) {
    const int d = threadIdx.x, b = blockIdx.x;
    float s = 0.f;
    for (int c = 0; c < 144; ++c) s += pS[((long long)b * 144 + c) * Cc + d];
    colS[b * Cc + d] = s;
}

// ---------------- K_ctx2: ctx GEMM with transpose-on-load staging.
// ctxp[kc][b][d][e] = sum_{n in chunk} Kexp[n][d] * V[n][e], inputs row-major [n][*].
// grid (4, KS2, Bb): x = (d-tile<<1)|e-tile (128x128), block 256. BK=64 n, 18 iters.
__global__ __launch_bounds__(256) void k_ctx2(const u16* __restrict__ Kexp,
                                              const u16* __restrict__ V,
                                              float* __restrict__ ctxp) {
    __shared__ alignas(16) unsigned char smemRaw[32768];
    u16* Asm = reinterpret_cast<u16*>(smemRaw);            // [128 d][64 n] swizzled
    u16* Bsm = reinterpret_cast<u16*>(smemRaw + 16384);    // [128 e][64 n]
    float (*patch)[16][68] = reinterpret_cast<float (*)[16][68]>(smemRaw);

    const int t = threadIdx.x;
    const int b = blockIdx.z, kc = blockIdx.y;
    const int d0 = (blockIdx.x >> 1) * 128, e0 = (blockIdx.x & 1) * 128;
    const int l = t & 63, w = t >> 6;
    const int wr = w >> 1, wc = w & 1;
    const int frow = l & 15, fk = (l >> 4) << 3;
    const int sr = t & 63, sw = t >> 6;    // staging: n-row, wave(=64B line)

    f32x4 acc[4][4] = {};

    for (int kt = 0; kt < 18; ++kt) {
        const long long nb = (long long)b * Nn + kc * 1152 + kt * 64;
        int4 av[4], bv[4];
#pragma unroll
        for (int j = 0; j < 4; ++j) {
            const int c8 = sw * 4 + j;     // 16B chunk 0..15 within 128-wide tile
            av[j] = *reinterpret_cast<const int4*>(Kexp + (nb + sr) * Cc + d0 + c8 * 8);
            bv[j] = *reinterpret_cast<const int4*>(V + (nb + sr) * Cc + e0 + c8 * 8);
        }
        __syncthreads();
#pragma unroll
        for (int j = 0; j < 4; ++j) {
            const u16* pa = reinterpret_cast<const u16*>(&av[j]);
            const u16* pb = reinterpret_cast<const u16*>(&bv[j]);
#pragma unroll
            for (int e8 = 0; e8 < 8; ++e8) {
                const int dd = (sw * 4 + j) * 8 + e8;
                const int col = sr ^ (e8 << 3);
                Asm[dd * 64 + col] = pa[e8];
                Bsm[dd * 64 + col] = pb[e8];
            }
        }
        __syncthreads();
#pragma unroll
        for (int kf = 0; kf < 2; ++kf) {
            short8 af[4], bf[4];
            const int kk = kf * 32 + fk;
#pragma unroll
            for (int mi = 0; mi < 4; ++mi) {
                const int rw_ = wr * 64 + mi * 16 + frow;
                af[mi] = *reinterpret_cast<const short8*>(&Asm[rw_ * 64 + (kk ^ ((rw_ & 7) << 3))]);
            }
#pragma unroll
            for (int ni = 0; ni < 4; ++ni) {
                const int rw_ = wc * 64 + ni * 16 + frow;
                bf[ni] = *reinterpret_cast<const short8*>(&Bsm[rw_ * 64 + (kk ^ ((rw_ & 7) << 3))]);
            }
#pragma unroll
            for (int mi = 0; mi < 4; ++mi)
#pragma unroll
                for (int ni = 0; ni < 4; ++ni)
                    acc[mi][ni] = __builtin_amdgcn_mfma_f32_16x16x32_bf16(af[mi], bf[ni], acc[mi][ni], 0, 0, 0);
        }
    }

    __syncthreads();
    float* Cg = ctxp + ((long long)kc * Bb + b) * Cc * Cc;
    const int crow0 = (l >> 4) * 4, ccol = l & 15;
#pragma unroll
    for (int mi = 0; mi < 4; ++mi) {
#pragma unroll
        for (int ni = 0; ni < 4; ++ni)
#pragma unroll
            for (int r_ = 0; r_ < 4; ++r_)
                patch[w][crow0 + r_][ni * 16 + ccol] = acc[mi][ni][r_];
        asm volatile("s_waitcnt lgkmcnt(0)" ::: "memory");
        __builtin_amdgcn_sched_barrier(0);
#pragma unroll
        for (int row = 0; row < 16; ++row)
            Cg[(long long)(d0 + wr * 64 + mi * 16 + row) * Cc + e0 + wc * 64 + l] = patch[w][row][l];
        asm volatile("s_waitcnt lgkmcnt(0)" ::: "memory");
        __builtin_amdgcn_sched_barrier(0);
    }
}

// ---------------- K3b: split-K reduction + 1/colS row scale
__global__ __launch_bounds__(256) void k_ctxred(const float* __restrict__ ctxp,
                                                const float* __restrict__ colS,
                                                float* __restrict__ ctx) {
    const long long i4 = ((long long)blockIdx.x * 256 + threadIdx.x) * 4;
    float4 s = make_float4(0.f, 0.f, 0.f, 0.f);
    for (int kc = 0; kc < KS2; ++kc) {
        const float4 v = *reinterpret_cast<const float4*>(ctxp + (long long)kc * (Bb * Cc * Cc) + i4);
        s.x += v.x; s.y += v.y; s.z += v.z; s.w += v.w;
    }
    const int b = (int)(i4 >> 16);
    const int d = ((int)(i4 >> 8)) & 255;
    const float inv = 1.0f / colS[b * Cc + d];
    s.x *= inv; s.y *= inv; s.z *= inv; s.w *= inv;
    *reinterpret_cast<float4*>(ctx + i4) = s;
}

// ---------------- K4: rank + combined top-k softmax coefficients. block per (b,d) row.
__global__ __launch_bounds__(256) void k_rank(const float* __restrict__ ctx,
                                              const float* __restrict__ aw,
                                              float* __restrict__ Ac) {
    __shared__ float row[256];
    __shared__ float red[256];
    const int d = blockIdx.x, b = blockIdx.y, e = threadIdx.x;
    const float c = ctx[((long long)(b * Cc + d)) * Cc + e];
    row[e] = c;
    __syncthreads();
    int p = 0;
    for (int j = 0; j < 256; ++j) {
        const float cj = row[j];
        p += (cj > c) || (cj == c && j < e);  // stable top_k rank (0-based)
    }
    red[e] = c; __syncthreads();
    for (int s_ = 128; s_; s_ >>= 1) { if (e < s_) red[e] = fmaxf(red[e], red[e + s_]); __syncthreads(); }
    const float m = red[0];
    const float ex = __expf(c - m);
    const int kks[4] = {128, 170, 192, 204};
    float Zv[4];
#pragma unroll
    for (int i = 0; i < 4; ++i) {
        __syncthreads();
        red[e] = (p < kks[i]) ? ex : 0.0f;
        __syncthreads();
        for (int s_ = 128; s_; s_ >>= 1) { if (e < s_) red[e] += red[e + s_]; __syncthreads(); }
        Zv[i] = red[0];
    }
    float wsum = 0.0f;
#pragma unroll
    for (int i = 0; i < 4; ++i)
        if (p < kks[i]) wsum += aw[i] / Zv[i];
    Ac[((long long)(b * Cc + d)) * Cc + e] = ex * wsum;
}

// ---------------- K5: WA[b,o,e] = sum_d W[o,d] * A[b,d,e] -> bf16. grid (32, 8), block 256.
__global__ __launch_bounds__(256) void k_wa(const float* __restrict__ W,
                                            const float* __restrict__ Ac,
                                            u16* __restrict__ WAb16) {
    __shared__ float As[16][64], Bs[16][64];
    const int b = blockIdx.y;
    const int o0 = (blockIdx.x >> 2) * 64, e0 = (blockIdx.x & 3) * 64;
    const int t = threadIdx.x, tx = t & 15, ty = t >> 4;
    const int a_oo = t >> 2, a_k4 = (t & 3) * 4;
    const int b_kk = t >> 4, b_e4 = (t & 15) * 4;
    float acc[4][4] = {{0.f}};
    for (int kd = 0; kd < 256; kd += 16) {
        const float4 wv = *reinterpret_cast<const float4*>(W + (o0 + a_oo) * Cc + kd + a_k4);
        const float4 av = *reinterpret_cast<const float4*>(Ac + ((long long)(b * Cc + kd + b_kk)) * Cc + e0 + b_e4);
        __syncthreads();
        As[a_k4 + 0][a_oo] = wv.x; As[a_k4 + 1][a_oo] = wv.y;
        As[a_k4 + 2][a_oo] = wv.z; As[a_k4 + 3][a_oo] = wv.w;
        *reinterpret_cast<float4*>(&Bs[b_kk][b_e4]) = av;
        __syncthreads();
#pragma unroll
        for (int kk = 0; kk < 16; ++kk) {
            const float4 a4 = *reinterpret_cast<const float4*>(&As[kk][ty * 4]);
            const float4 b4 = *reinterpret_cast<const float4*>(&Bs[kk][tx * 4]);
            const float aa[4] = {a4.x, a4.y, a4.z, a4.w};
            const float bb[4] = {b4.x, b4.y, b4.z, b4.w};
#pragma unroll
            for (int i = 0; i < 4; ++i)
#pragma unroll
                for (int j = 0; j < 4; ++j) acc[i][j] = fmaf(aa[i], bb[j], acc[i][j]);
        }
    }
#pragma unroll
    for (int i = 0; i < 4; ++i) {
        int2 pk;
        pk.x = (int)((unsigned)f2bf(acc[i][0]) | ((unsigned)f2bf(acc[i][1]) << 16));
        pk.y = (int)((unsigned)f2bf(acc[i][2]) | ((unsigned)f2bf(acc[i][3]) << 16));
        *reinterpret_cast<int2*>(WAb16 + ((long long)(b * Oo + o0 + ty * 4 + i)) * Cc + e0 + tx * 4) = pk;
    }
}

// ---------------- K7: fused reprojection GEMM + row-scale + bias + LN(512) + transposed store.
// A = Kexp (unnormalized); softmax row-normalization pulled into the f32 epilogue.
// grid (288, 1, 8), block 256 (4 waves x 128 o), XCD-swizzled n-tiles, nt stores.
__global__ __launch_bounds__(256, 3) void k_rpln(const u16* __restrict__ Kexp,
                                                 const float* __restrict__ rowsum,
                                                 const u16* __restrict__ WAb16,
                                                 const float* __restrict__ rbias,
                                                 const float* __restrict__ nw,
                                                 const float* __restrict__ nb,
                                                 float* __restrict__ out) {
    __shared__ float patch[4][16][36];          // per-wave 16 o x 32 n
    __shared__ float psum[32][4], psq[32][4];
    __shared__ float muA[32], rsA[32];
    __shared__ float irow[32];

    const int t = threadIdx.x;
    const int b = blockIdx.z;
    const int nt_ = (blockIdx.x & 7) * 36 + (blockIdx.x >> 3);   // XCD swizzle (288 = 8*36)
    const int n0 = nt_ * 32;
    const int l = t & 63, w = t >> 6;           // wave w owns o = w*128..
    const int frow = l & 15, fk = (l >> 4) << 3;
    const int hi = l >> 4;

    if (t < 32) irow[t] = 1.0f / rowsum[(long long)b * Nn + n0 + t];

    f32x4 acc[2][8] = {};

    const u16* Aq = Kexp + ((long long)b * Nn + n0) * Cc;
    const u16* Bw = WAb16 + ((long long)b * Oo + w * 128) * Cc;

    // preload ALL A fragments: 2 n-halves x 8 K-steps
    int4 aF[2][8];
#pragma unroll
    for (int mi = 0; mi < 2; ++mi)
#pragma unroll
        for (int s = 0; s < 8; ++s)
            aF[mi][s] = *reinterpret_cast<const int4*>(Aq + (mi * 16 + frow) * Cc + s * 32 + fk);

    int4 bC[8], bN[8];
#pragma unroll
    for (int ni = 0; ni < 8; ++ni)
        bC[ni] = *reinterpret_cast<const int4*>(Bw + (ni * 16 + frow) * Cc + fk);

#pragma unroll
    for (int s = 0; s < 8; ++s) {
        if (s < 7) {
            const int kk = (s + 1) * 32 + fk;
#pragma unroll
            for (int ni = 0; ni < 8; ++ni)
                bN[ni] = *reinterpret_cast<const int4*>(Bw + (ni * 16 + frow) * Cc + kk);
        }
#pragma unroll
        for (int mi = 0; mi < 2; ++mi)
#pragma unroll
            for (int ni = 0; ni < 8; ++ni)
                acc[mi][ni] = __builtin_amdgcn_mfma_f32_16x16x32_bf16(
                    __builtin_bit_cast(short8, aF[mi][s]), __builtin_bit_cast(short8, bC[ni]),
                    acc[mi][ni], 0, 0, 0);
        if (s < 7) {
#pragma unroll
            for (int ni = 0; ni < 8; ++ni) bC[ni] = bN[ni];
        }
    }

    __syncthreads();   // irow visible
    // ---- epilogue: row-scale (softmax denominator) + bias
#pragma unroll
    for (int ni = 0; ni < 8; ++ni) {
        const float bb = rbias[w * 128 + ni * 16 + frow];
#pragma unroll
        for (int mi = 0; mi < 2; ++mi)
#pragma unroll
            for (int r_ = 0; r_ < 4; ++r_) {
                const int rw_ = mi * 16 + hi * 4 + r_;
                acc[mi][ni][r_] = acc[mi][ni][r_] * irow[rw_] + bb;
            }
    }
    // per-row LN partials over this wave's 128 cols
#pragma unroll
    for (int mi = 0; mi < 2; ++mi)
#pragma unroll
        for (int r_ = 0; r_ < 4; ++r_) {
            float s = 0.f, q = 0.f;
#pragma unroll
            for (int ni = 0; ni < 8; ++ni) { const float v = acc[mi][ni][r_]; s += v; q += v * v; }
#pragma unroll
            for (int m = 8; m; m >>= 1) { s += __shfl_xor(s, m); q += __shfl_xor(q, m); }
            if (frow == 0) {
                const int row = mi * 16 + hi * 4 + r_;
                psum[row][w] = s; psq[row][w] = q;
            }
        }
    __syncthreads();
    if (t < 32) {
        const float s = psum[t][0] + psum[t][1] + psum[t][2] + psum[t][3];
        const float q = psq[t][0] + psq[t][1] + psq[t][2] + psq[t][3];
        const float m = s * (1.0f / Oo);
        muA[t] = m;
        rsA[t] = rsqrtf(q * (1.0f / Oo) - m * m + LN_EPS);
    }
    __syncthreads();

    float nwv[8], nbv[8];
#pragma unroll
    for (int ni = 0; ni < 8; ++ni) {
        const int o = w * 128 + ni * 16 + frow;
        nwv[ni] = nw[o]; nbv[ni] = nb[o];
    }

    // per ni: wave-private 16o x 32n patch -> nontemporal f32x4 stores.
#pragma unroll
    for (int ni = 0; ni < 8; ++ni) {
#pragma unroll
        for (int mi = 0; mi < 2; ++mi)
#pragma unroll
            for (int r_ = 0; r_ < 4; ++r_) {
                const int nl = mi * 16 + hi * 4 + r_;              // 0..31
                patch[w][frow][nl] = (acc[mi][ni][r_] - muA[nl]) * rsA[nl] * nwv[ni] + nbv[ni];
            }
        asm volatile("s_waitcnt lgkmcnt(0)" ::: "memory");
        __builtin_amdgcn_sched_barrier(0);
#pragma unroll
        for (int p = 0; p < 2; ++p) {
            const int o_loc = p * 8 + (l >> 3);                    // 0..15
            const int colf4 = l & 7;                               // 0..7
            const f32x4 v = *reinterpret_cast<const f32x4*>(&patch[w][o_loc][colf4 * 4]);
            const int o_g = w * 128 + ni * 16 + o_loc;
            __builtin_nontemporal_store(v,
                reinterpret_cast<f32x4*>(&out[((long long)(b * Oo + o_g)) * Nn + n0 + colf4 * 4]));
        }
        asm volatile("s_waitcnt lgkmcnt(0)" ::: "memory");
        __builtin_amdgcn_sched_barrier(0);
    }
}

extern "C" void kernel_launch(void* const* d_in, const int* in_sizes, int n_in,
                              void* d_out, int out_size, void* d_ws, size_t ws_size,
                              hipStream_t stream) {
    (void)in_sizes; (void)n_in; (void)out_size; (void)ws_size;
    const float* x1    = (const float*)d_in[0];
    const float* x2    = (const float*)d_in[1];
    const float* n1w   = (const float*)d_in[2];
    const float* n1b   = (const float*)d_in[3];
    const float* rw    = (const float*)d_in[4];
    const float* rbias = (const float*)d_in[5];
    const float* n2w   = (const float*)d_in[6];
    const float* n2b   = (const float*)d_in[7];
    const float* aw    = (const float*)d_in[8];
    float* out = (float*)d_out;

    // d_out doubles as scratch for V (dead before k_rpln's final overwrite).
    u16* V = (u16*)d_out;

    float* ws = (float*)d_ws;
    size_t off = 0;
    u16*   Kexp   = (u16*)(ws + off); off += (size_t)Bb * Nn * Cc / 2;
    float* ctxp   = ws + off; off += (size_t)KS2 * Bb * Cc * Cc;
    float* ctx    = ws + off; off += (size_t)Bb * Cc * Cc;
    float* Ac     = ws + off; off += (size_t)Bb * Cc * Cc;
    u16*   WAb16  = (u16*)(ws + off); off += (size_t)Bb * Oo * Cc / 2;
    float* pS     = ws + off; off += (size_t)Bb * 144 * Cc;
    float* colS   = ws + off; off += (size_t)Bb * Cc;
    float* rowsum = ws + off; off += (size_t)Bb * Nn;

    k_pre<<<dim3(144, 1, Bb), 512, 0, stream>>>(x2, n1w, n1b, Kexp, rowsum, pS, 1);
    k_pre<<<dim3(144, 1, Bb), 512, 0, stream>>>(x1, n1w, n1b, V, rowsum, pS, 0);
    k_colcomb<<<dim3(Bb), 256, 0, stream>>>(pS, colS);
    k_ctx2<<<dim3(4, KS2, Bb), 256, 0, stream>>>(Kexp, V, ctxp);
    k_ctxred<<<dim3(512), 256, 0, stream>>>(ctxp, colS, ctx);
    k_rank<<<dim3(Cc, Bb), 256, 0, stream>>>(ctx, aw, Ac);
    k_wa<<<dim3(32, Bb), 256, 0, stream>>>(rw, Ac, WAb16);
    k_rpln<<<dim3(288, 1, Bb), 256, 0, stream>>>(Kexp, rowsum, WAb16, rbias, n2w, n2b, out);
}

// Round 17
// 224.353 us; speedup vs baseline: 1.2702x; 1.0238x over previous
//
#include <hip/hip_runtime.h>
#include <math.h>

typedef __attribute__((ext_vector_type(8))) short short8;
typedef __attribute__((ext_vector_type(4))) float f32x4;
typedef unsigned short u16;
typedef unsigned int u32;

constexpr int Bb = 8;
constexpr int Nn = 9216;   // 96*96
constexpr int Cc = 256;    // = D
constexpr int Oo = 512;    // 2C
constexpr float LN_EPS = 1e-5f;
constexpr int KS2 = 16;    // ctx GEMM split-K chunks (9216 = 16*576)

static __device__ __forceinline__ u16 f2bf(float f) {
    unsigned u = __builtin_bit_cast(unsigned, f);
    u += 0x7fffu + ((u >> 16) & 1u);   // RNE
    return (u16)(u >> 16);
}
static __device__ __forceinline__ float bf2f(u16 u) {
    return __builtin_bit_cast(float, (unsigned)u << 16);
}

// ---------------- K_pre v4: fused per-input pass (512 threads, 64n x 256d per block).
// NO transposes: writes row-major bf16 (exp'd if doExp). doExp also writes rowsum[n]
// and pS column partials (shuffle + cross-wave LDS reduce). All global writes contiguous.
__global__ __launch_bounds__(512, 2) void k_pre(const float* __restrict__ src,
                                                const float* __restrict__ lnw,
                                                const float* __restrict__ lnb,
                                                u16* __restrict__ dst,
                                                float* __restrict__ rowsum,
                                                float* __restrict__ pS,
                                                int doExp) {
    __shared__ float wsh[256], bsh[256];
    __shared__ float wred[8][256];
    const int b = blockIdx.z;
    const int nc = (blockIdx.x & 7) * 18 + (blockIdx.x >> 3);   // XCD swizzle (144 = 8*18)
    const int n0 = nc * 64;
    const int t = threadIdx.x;
    if (t < 256) { wsh[t] = lnw[t]; bsh[t] = lnb[t]; }
    __syncthreads();

    const int r = t >> 3;            // 0..63
    const int g = t & 7;             // 0..7
    const int wv = t >> 6;           // wave 0..7
    const long long row = (long long)b * Nn + n0 + r;
    const float* rowp = src + row * Cc;

    float4 v[8];
#pragma unroll
    for (int i = 0; i < 8; ++i)
        v[i] = *reinterpret_cast<const float4*>(rowp + g * 4 + i * 32);

    float s = 0.f, q = 0.f;
#pragma unroll
    for (int i = 0; i < 8; ++i) {
        s += v[i].x + v[i].y + v[i].z + v[i].w;
        q += v[i].x * v[i].x + v[i].y * v[i].y + v[i].z * v[i].z + v[i].w * v[i].w;
    }
    s += __shfl_xor(s, 1); s += __shfl_xor(s, 2); s += __shfl_xor(s, 4);
    q += __shfl_xor(q, 1); q += __shfl_xor(q, 2); q += __shfl_xor(q, 4);
    const float mu = s * (1.0f / Cc);
    const float rstd = rsqrtf(q * (1.0f / Cc) - mu * mu + LN_EPS);

    float se = 0.f;
    u16 h[8][4];
#pragma unroll
    for (int i = 0; i < 8; ++i) {
        const int d = g * 4 + i * 32;
        const float4 w4 = *reinterpret_cast<const float4*>(&wsh[d]);
        const float4 b4 = *reinterpret_cast<const float4*>(&bsh[d]);
        v[i].x = (v[i].x - mu) * rstd * w4.x + b4.x;
        v[i].y = (v[i].y - mu) * rstd * w4.y + b4.y;
        v[i].z = (v[i].z - mu) * rstd * w4.z + b4.z;
        v[i].w = (v[i].w - mu) * rstd * w4.w + b4.w;
        if (doExp) {
            v[i].x = __expf(v[i].x); v[i].y = __expf(v[i].y);
            v[i].z = __expf(v[i].z); v[i].w = __expf(v[i].w);
            se += v[i].x + v[i].y + v[i].z + v[i].w;
        }
        h[i][0] = f2bf(v[i].x); h[i][1] = f2bf(v[i].y);
        h[i][2] = f2bf(v[i].z); h[i][3] = f2bf(v[i].w);
        int2 pk;
        pk.x = (int)((unsigned)h[i][0] | ((unsigned)h[i][1] << 16));
        pk.y = (int)((unsigned)h[i][2] | ((unsigned)h[i][3] << 16));
        *reinterpret_cast<int2*>(dst + row * Cc + d) = pk;
    }

    if (doExp) {
        se += __shfl_xor(se, 1); se += __shfl_xor(se, 2); se += __shfl_xor(se, 4);
        if (g == 0) rowsum[row] = se;
        // column partials: sum bf16-rounded values over the block's 64 n-rows.
#pragma unroll
        for (int i = 0; i < 8; ++i) {
            float c0 = bf2f(h[i][0]), c1 = bf2f(h[i][1]);
            float c2 = bf2f(h[i][2]), c3 = bf2f(h[i][3]);
#pragma unroll
            for (int m = 8; m <= 32; m <<= 1) {
                c0 += __shfl_xor(c0, m); c1 += __shfl_xor(c1, m);
                c2 += __shfl_xor(c2, m); c3 += __shfl_xor(c3, m);
            }
            if ((t & 63) < 8) {          // lane == g: holds wave-partial
                const int d = g * 4 + i * 32;
                wred[wv][d + 0] = c0; wred[wv][d + 1] = c1;
                wred[wv][d + 2] = c2; wred[wv][d + 3] = c3;
            }
        }
        __syncthreads();
        if (t < 256) {
            float ss = 0.f;
#pragma unroll
            for (int i = 0; i < 8; ++i) ss += wred[i][t];
            pS[((long long)b * 144 + nc) * Cc + t] = ss;
        }
    }
}

// ---------------- K2b: colS[b][d] = sum over 144 chunks
__global__ __launch_bounds__(256) void k_colcomb(const float* __restrict__ pS,
                                                 float* __restrict__ colS) {
    const int d = threadIdx.x, b = blockIdx.x;
    float s = 0.f;
    for (int c = 0; c < 144; ++c) s += pS[((long long)b * 144 + c) * Cc + d];
    colS[b * Cc + d] = s;
}

// ---------------- K_ctx2: ctx GEMM with transpose-on-load staging.
// ctxp[kc][b][d][e] = sum_{n in chunk} Kexp[n][d] * V[n][e], inputs row-major [n][*].
// grid (4, KS2=16, Bb): x = (d-tile<<1)|e-tile (128x128), block 256. BK=64 n, 9 iters.
__global__ __launch_bounds__(256) void k_ctx2(const u16* __restrict__ Kexp,
                                              const u16* __restrict__ V,
                                              float* __restrict__ ctxp) {
    __shared__ alignas(16) unsigned char smemRaw[32768];
    u16* Asm = reinterpret_cast<u16*>(smemRaw);            // [128 d][64 n] swizzled
    u16* Bsm = reinterpret_cast<u16*>(smemRaw + 16384);    // [128 e][64 n]
    float (*patch)[16][68] = reinterpret_cast<float (*)[16][68]>(smemRaw);

    const int t = threadIdx.x;
    const int b = blockIdx.z, kc = blockIdx.y;
    const int d0 = (blockIdx.x >> 1) * 128, e0 = (blockIdx.x & 1) * 128;
    const int l = t & 63, w = t >> 6;
    const int wr = w >> 1, wc = w & 1;
    const int frow = l & 15, fk = (l >> 4) << 3;
    const int sr = t & 63, sw = t >> 6;    // staging: n-row, wave(=64B line)

    f32x4 acc[4][4] = {};

    for (int kt = 0; kt < 9; ++kt) {
        const long long nb = (long long)b * Nn + kc * 576 + kt * 64;
        int4 av[4], bv[4];
#pragma unroll
        for (int j = 0; j < 4; ++j) {
            const int c8 = sw * 4 + j;     // 16B chunk 0..15 within 128-wide tile
            av[j] = *reinterpret_cast<const int4*>(Kexp + (nb + sr) * Cc + d0 + c8 * 8);
            bv[j] = *reinterpret_cast<const int4*>(V + (nb + sr) * Cc + e0 + c8 * 8);
        }
        __syncthreads();
#pragma unroll
        for (int j = 0; j < 4; ++j) {
            const u16* pa = reinterpret_cast<const u16*>(&av[j]);
            const u16* pb = reinterpret_cast<const u16*>(&bv[j]);
#pragma unroll
            for (int e8 = 0; e8 < 8; ++e8) {
                const int dd = (sw * 4 + j) * 8 + e8;
                const int col = sr ^ (e8 << 3);
                Asm[dd * 64 + col] = pa[e8];
                Bsm[dd * 64 + col] = pb[e8];
            }
        }
        __syncthreads();
#pragma unroll
        for (int kf = 0; kf < 2; ++kf) {
            short8 af[4], bf[4];
            const int kk = kf * 32 + fk;
#pragma unroll
            for (int mi = 0; mi < 4; ++mi) {
                const int rw_ = wr * 64 + mi * 16 + frow;
                af[mi] = *reinterpret_cast<const short8*>(&Asm[rw_ * 64 + (kk ^ ((rw_ & 7) << 3))]);
            }
#pragma unroll
            for (int ni = 0; ni < 4; ++ni) {
                const int rw_ = wc * 64 + ni * 16 + frow;
                bf[ni] = *reinterpret_cast<const short8*>(&Bsm[rw_ * 64 + (kk ^ ((rw_ & 7) << 3))]);
            }
#pragma unroll
            for (int mi = 0; mi < 4; ++mi)
#pragma unroll
                for (int ni = 0; ni < 4; ++ni)
                    acc[mi][ni] = __builtin_amdgcn_mfma_f32_16x16x32_bf16(af[mi], bf[ni], acc[mi][ni], 0, 0, 0);
        }
    }

    __syncthreads();
    float* Cg = ctxp + ((long long)kc * Bb + b) * Cc * Cc;
    const int crow0 = (l >> 4) * 4, ccol = l & 15;
#pragma unroll
    for (int mi = 0; mi < 4; ++mi) {
#pragma unroll
        for (int ni = 0; ni < 4; ++ni)
#pragma unroll
            for (int r_ = 0; r_ < 4; ++r_)
                patch[w][crow0 + r_][ni * 16 + ccol] = acc[mi][ni][r_];
        asm volatile("s_waitcnt lgkmcnt(0)" ::: "memory");
        __builtin_amdgcn_sched_barrier(0);
#pragma unroll
        for (int row = 0; row < 16; ++row)
            Cg[(long long)(d0 + wr * 64 + mi * 16 + row) * Cc + e0 + wc * 64 + l] = patch[w][row][l];
        asm volatile("s_waitcnt lgkmcnt(0)" ::: "memory");
        __builtin_amdgcn_sched_barrier(0);
    }
}

// ---------------- K4: fused split-K reduce + colS scale + rank + combined top-k coeffs.
// block per (b,d) row; thread e sums 16 ctxp slices (coalesced 256-B runs per wave).
__global__ __launch_bounds__(256) void k_rankred(const float* __restrict__ ctxp,
                                                 const float* __restrict__ colS,
                                                 const float* __restrict__ aw,
                                                 float* __restrict__ Ac) {
    __shared__ float row[256];
    __shared__ float red[256];
    const int d = blockIdx.x, b = blockIdx.y, e = threadIdx.x;
    float c = 0.f;
#pragma unroll
    for (int kc = 0; kc < KS2; ++kc)
        c += ctxp[(((long long)kc * Bb + b) * Cc + d) * Cc + e];
    c *= 1.0f / colS[b * Cc + d];
    row[e] = c;
    __syncthreads();
    int p = 0;
    for (int j = 0; j < 256; ++j) {
        const float cj = row[j];
        p += (cj > c) || (cj == c && j < e);  // stable top_k rank (0-based)
    }
    red[e] = c; __syncthreads();
    for (int s_ = 128; s_; s_ >>= 1) { if (e < s_) red[e] = fmaxf(red[e], red[e + s_]); __syncthreads(); }
    const float m = red[0];
    const float ex = __expf(c - m);
    const int kks[4] = {128, 170, 192, 204};
    float Zv[4];
#pragma unroll
    for (int i = 0; i < 4; ++i) {
        __syncthreads();
        red[e] = (p < kks[i]) ? ex : 0.0f;
        __syncthreads();
        for (int s_ = 128; s_; s_ >>= 1) { if (e < s_) red[e] += red[e + s_]; __syncthreads(); }
        Zv[i] = red[0];
    }
    float wsum = 0.0f;
#pragma unroll
    for (int i = 0; i < 4; ++i)
        if (p < kks[i]) wsum += aw[i] / Zv[i];
    Ac[((long long)(b * Cc + d)) * Cc + e] = ex * wsum;
}

// ---------------- K5: WA[b,o,e] = sum_d W[o,d] * A[b,d,e] -> bf16. grid (32, 8), block 256.
__global__ __launch_bounds__(256) void k_wa(const float* __restrict__ W,
                                            const float* __restrict__ Ac,
                                            u16* __restrict__ WAb16) {
    __shared__ float As[16][64], Bs[16][64];
    const int b = blockIdx.y;
    const int o0 = (blockIdx.x >> 2) * 64, e0 = (blockIdx.x & 3) * 64;
    const int t = threadIdx.x, tx = t & 15, ty = t >> 4;
    const int a_oo = t >> 2, a_k4 = (t & 3) * 4;
    const int b_kk = t >> 4, b_e4 = (t & 15) * 4;
    float acc[4][4] = {{0.f}};
    for (int kd = 0; kd < 256; kd += 16) {
        const float4 wv = *reinterpret_cast<const float4*>(W + (o0 + a_oo) * Cc + kd + a_k4);
        const float4 av = *reinterpret_cast<const float4*>(Ac + ((long long)(b * Cc + kd + b_kk)) * Cc + e0 + b_e4);
        __syncthreads();
        As[a_k4 + 0][a_oo] = wv.x; As[a_k4 + 1][a_oo] = wv.y;
        As[a_k4 + 2][a_oo] = wv.z; As[a_k4 + 3][a_oo] = wv.w;
        *reinterpret_cast<float4*>(&Bs[b_kk][b_e4]) = av;
        __syncthreads();
#pragma unroll
        for (int kk = 0; kk < 16; ++kk) {
            const float4 a4 = *reinterpret_cast<const float4*>(&As[kk][ty * 4]);
            const float4 b4 = *reinterpret_cast<const float4*>(&Bs[kk][tx * 4]);
            const float aa[4] = {a4.x, a4.y, a4.z, a4.w};
            const float bb[4] = {b4.x, b4.y, b4.z, b4.w};
#pragma unroll
            for (int i = 0; i < 4; ++i)
#pragma unroll
                for (int j = 0; j < 4; ++j) acc[i][j] = fmaf(aa[i], bb[j], acc[i][j]);
        }
    }
#pragma unroll
    for (int i = 0; i < 4; ++i) {
        int2 pk;
        pk.x = (int)((unsigned)f2bf(acc[i][0]) | ((unsigned)f2bf(acc[i][1]) << 16));
        pk.y = (int)((unsigned)f2bf(acc[i][2]) | ((unsigned)f2bf(acc[i][3]) << 16));
        *reinterpret_cast<int2*>(WAb16 + ((long long)(b * Oo + o0 + ty * 4 + i)) * Cc + e0 + tx * 4) = pk;
    }
}

// ---------------- K7: fused reprojection GEMM + row-scale + bias + LN(512) + transposed store.
// A = Kexp (unnormalized); softmax row-normalization pulled into the f32 epilogue.
// grid (288, 1, 8), block 256 (4 waves x 128 o), XCD-swizzled n-tiles, nt stores.
__global__ __launch_bounds__(256, 3) void k_rpln(const u16* __restrict__ Kexp,
                                                 const float* __restrict__ rowsum,
                                                 const u16* __restrict__ WAb16,
                                                 const float* __restrict__ rbias,
                                                 const float* __restrict__ nw,
                                                 const float* __restrict__ nb,
                                                 float* __restrict__ out) {
    __shared__ float patch[4][16][36];          // per-wave 16 o x 32 n
    __shared__ float psum[32][4], psq[32][4];
    __shared__ float muA[32], rsA[32];
    __shared__ float irow[32];

    const int t = threadIdx.x;
    const int b = blockIdx.z;
    const int nt_ = (blockIdx.x & 7) * 36 + (blockIdx.x >> 3);   // XCD swizzle (288 = 8*36)
    const int n0 = nt_ * 32;
    const int l = t & 63, w = t >> 6;           // wave w owns o = w*128..
    const int frow = l & 15, fk = (l >> 4) << 3;
    const int hi = l >> 4;

    if (t < 32) irow[t] = 1.0f / rowsum[(long long)b * Nn + n0 + t];

    f32x4 acc[2][8] = {};

    const u16* Aq = Kexp + ((long long)b * Nn + n0) * Cc;
    const u16* Bw = WAb16 + ((long long)b * Oo + w * 128) * Cc;

    // preload ALL A fragments: 2 n-halves x 8 K-steps
    int4 aF[2][8];
#pragma unroll
    for (int mi = 0; mi < 2; ++mi)
#pragma unroll
        for (int s = 0; s < 8; ++s)
            aF[mi][s] = *reinterpret_cast<const int4*>(Aq + (mi * 16 + frow) * Cc + s * 32 + fk);

    int4 bC[8], bN[8];
#pragma unroll
    for (int ni = 0; ni < 8; ++ni)
        bC[ni] = *reinterpret_cast<const int4*>(Bw + (ni * 16 + frow) * Cc + fk);

#pragma unroll
    for (int s = 0; s < 8; ++s) {
        if (s < 7) {
            const int kk = (s + 1) * 32 + fk;
#pragma unroll
            for (int ni = 0; ni < 8; ++ni)
                bN[ni] = *reinterpret_cast<const int4*>(Bw + (ni * 16 + frow) * Cc + kk);
        }
#pragma unroll
        for (int mi = 0; mi < 2; ++mi)
#pragma unroll
            for (int ni = 0; ni < 8; ++ni)
                acc[mi][ni] = __builtin_amdgcn_mfma_f32_16x16x32_bf16(
                    __builtin_bit_cast(short8, aF[mi][s]), __builtin_bit_cast(short8, bC[ni]),
                    acc[mi][ni], 0, 0, 0);
        if (s < 7) {
#pragma unroll
            for (int ni = 0; ni < 8; ++ni) bC[ni] = bN[ni];
        }
    }

    __syncthreads();   // irow visible
    // ---- epilogue: row-scale (softmax denominator) + bias
#pragma unroll
    for (int ni = 0; ni < 8; ++ni) {
        const float bb = rbias[w * 128 + ni * 16 + frow];
#pragma unroll
        for (int mi = 0; mi < 2; ++mi)
#pragma unroll
            for (int r_ = 0; r_ < 4; ++r_) {
                const int rw_ = mi * 16 + hi * 4 + r_;
                acc[mi][ni][r_] = acc[mi][ni][r_] * irow[rw_] + bb;
            }
    }
    // per-row LN partials over this wave's 128 cols
#pragma unroll
    for (int mi = 0; mi < 2; ++mi)
#pragma unroll
        for (int r_ = 0; r_ < 4; ++r_) {
            float s = 0.f, q = 0.f;
#pragma unroll
            for (int ni = 0; ni < 8; ++ni) { const float v = acc[mi][ni][r_]; s += v; q += v * v; }
#pragma unroll
            for (int m = 8; m; m >>= 1) { s += __shfl_xor(s, m); q += __shfl_xor(q, m); }
            if (frow == 0) {
                const int row = mi * 16 + hi * 4 + r_;
                psum[row][w] = s; psq[row][w] = q;
            }
        }
    __syncthreads();
    if (t < 32) {
        const float s = psum[t][0] + psum[t][1] + psum[t][2] + psum[t][3];
        const float q = psq[t][0] + psq[t][1] + psq[t][2] + psq[t][3];
        const float m = s * (1.0f / Oo);
        muA[t] = m;
        rsA[t] = rsqrtf(q * (1.0f / Oo) - m * m + LN_EPS);
    }
    __syncthreads();

    float nwv[8], nbv[8];
#pragma unroll
    for (int ni = 0; ni < 8; ++ni) {
        const int o = w * 128 + ni * 16 + frow;
        nwv[ni] = nw[o]; nbv[ni] = nb[o];
    }

    // per ni: wave-private 16o x 32n patch -> nontemporal f32x4 stores.
#pragma unroll
    for (int ni = 0; ni < 8; ++ni) {
#pragma unroll
        for (int mi = 0; mi < 2; ++mi)
#pragma unroll
            for (int r_ = 0; r_ < 4; ++r_) {
                const int nl = mi * 16 + hi * 4 + r_;              // 0..31
                patch[w][frow][nl] = (acc[mi][ni][r_] - muA[nl]) * rsA[nl] * nwv[ni] + nbv[ni];
            }
        asm volatile("s_waitcnt lgkmcnt(0)" ::: "memory");
        __builtin_amdgcn_sched_barrier(0);
#pragma unroll
        for (int p = 0; p < 2; ++p) {
            const int o_loc = p * 8 + (l >> 3);                    // 0..15
            const int colf4 = l & 7;                               // 0..7
            const f32x4 v = *reinterpret_cast<const f32x4*>(&patch[w][o_loc][colf4 * 4]);
            const int o_g = w * 128 + ni * 16 + o_loc;
            __builtin_nontemporal_store(v,
                reinterpret_cast<f32x4*>(&out[((long long)(b * Oo + o_g)) * Nn + n0 + colf4 * 4]));
        }
        asm volatile("s_waitcnt lgkmcnt(0)" ::: "memory");
        __builtin_amdgcn_sched_barrier(0);
    }
}

extern "C" void kernel_launch(void* const* d_in, const int* in_sizes, int n_in,
                              void* d_out, int out_size, void* d_ws, size_t ws_size,
                              hipStream_t stream) {
    (void)in_sizes; (void)n_in; (void)out_size; (void)ws_size;
    const float* x1    = (const float*)d_in[0];
    const float* x2    = (const float*)d_in[1];
    const float* n1w   = (const float*)d_in[2];
    const float* n1b   = (const float*)d_in[3];
    const float* rw    = (const float*)d_in[4];
    const float* rbias = (const float*)d_in[5];
    const float* n2w   = (const float*)d_in[6];
    const float* n2b   = (const float*)d_in[7];
    const float* aw    = (const float*)d_in[8];
    float* out = (float*)d_out;

    // d_out doubles as scratch for V (dead before k_rpln's final overwrite).
    u16* V = (u16*)d_out;

    float* ws = (float*)d_ws;
    size_t off = 0;
    u16*   Kexp   = (u16*)(ws + off); off += (size_t)Bb * Nn * Cc / 2;
    float* ctxp   = ws + off; off += (size_t)KS2 * Bb * Cc * Cc;
    float* Ac     = ws + off; off += (size_t)Bb * Cc * Cc;
    u16*   WAb16  = (u16*)(ws + off); off += (size_t)Bb * Oo * Cc / 2;
    float* pS     = ws + off; off += (size_t)Bb * 144 * Cc;
    float* colS   = ws + off; off += (size_t)Bb * Cc;
    float* rowsum = ws + off; off += (size_t)Bb * Nn;

    k_pre<<<dim3(144, 1, Bb), 512, 0, stream>>>(x2, n1w, n1b, Kexp, rowsum, pS, 1);
    k_pre<<<dim3(144, 1, Bb), 512, 0, stream>>>(x1, n1w, n1b, V, rowsum, pS, 0);
    k_colcomb<<<dim3(Bb), 256, 0, stream>>>(pS, colS);
    k_ctx2<<<dim3(4, KS2, Bb), 256, 0, stream>>>(Kexp, V, ctxp);
    k_rankred<<<dim3(Cc, Bb), 256, 0, stream>>>(ctxp, colS, aw, Ac);
    k_wa<<<dim3(32, Bb), 256, 0, stream>>>(rw, Ac, WAb16);
    k_rpln<<<dim3(288, 1, Bb), 256, 0, stream>>>(Kexp, rowsum, WAb16, rbias, n2w, n2b, out);
}

// Round 18
// 220.931 us; speedup vs baseline: 1.2898x; 1.0155x over previous
//
#include <hip/hip_runtime.h>
#include <math.h>

typedef __attribute__((ext_vector_type(8))) short short8;
typedef __attribute__((ext_vector_type(4))) float f32x4;
typedef unsigned short u16;
typedef unsigned int u32;

constexpr int Bb = 8;
constexpr int Nn = 9216;   // 96*96
constexpr int Cc = 256;    // = D
constexpr int Oo = 512;    // 2C
constexpr float LN_EPS = 1e-5f;
constexpr int KS2 = 16;    // ctx GEMM split-K chunks (9216 = 16*576)

static __device__ __forceinline__ u16 f2bf(float f) {
    unsigned u = __builtin_bit_cast(unsigned, f);
    u += 0x7fffu + ((u >> 16) & 1u);   // RNE
    return (u16)(u >> 16);
}
static __device__ __forceinline__ float bf2f(u16 u) {
    return __builtin_bit_cast(float, (unsigned)u << 16);
}

// ---------------- K_pre v5: BOTH input passes in one launch. grid (144, 2, 8).
// y==0: x2-pass -> Kexp (exp'd) + rowsum + pS col partials. y==1: x1-pass -> V.
__global__ __launch_bounds__(512, 2) void k_pre(const float* __restrict__ x2,
                                                const float* __restrict__ x1,
                                                const float* __restrict__ lnw,
                                                const float* __restrict__ lnb,
                                                u16* __restrict__ Kexp,
                                                u16* __restrict__ V,
                                                float* __restrict__ rowsum,
                                                float* __restrict__ pS) {
    __shared__ float wsh[256], bsh[256];
    __shared__ float wred[8][256];
    const int b = blockIdx.z;
    const int doExp = (blockIdx.y == 0);
    const float* src = doExp ? x2 : x1;
    u16* dst = doExp ? Kexp : V;
    const int nc = (blockIdx.x & 7) * 18 + (blockIdx.x >> 3);   // XCD swizzle (144 = 8*18)
    const int n0 = nc * 64;
    const int t = threadIdx.x;
    if (t < 256) { wsh[t] = lnw[t]; bsh[t] = lnb[t]; }
    __syncthreads();

    const int r = t >> 3;            // 0..63
    const int g = t & 7;             // 0..7
    const int wv = t >> 6;           // wave 0..7
    const long long row = (long long)b * Nn + n0 + r;
    const float* rowp = src + row * Cc;

    float4 v[8];
#pragma unroll
    for (int i = 0; i < 8; ++i)
        v[i] = *reinterpret_cast<const float4*>(rowp + g * 4 + i * 32);

    float s = 0.f, q = 0.f;
#pragma unroll
    for (int i = 0; i < 8; ++i) {
        s += v[i].x + v[i].y + v[i].z + v[i].w;
        q += v[i].x * v[i].x + v[i].y * v[i].y + v[i].z * v[i].z + v[i].w * v[i].w;
    }
    s += __shfl_xor(s, 1); s += __shfl_xor(s, 2); s += __shfl_xor(s, 4);
    q += __shfl_xor(q, 1); q += __shfl_xor(q, 2); q += __shfl_xor(q, 4);
    const float mu = s * (1.0f / Cc);
    const float rstd = rsqrtf(q * (1.0f / Cc) - mu * mu + LN_EPS);

    float se = 0.f;
    u16 h[8][4];
#pragma unroll
    for (int i = 0; i < 8; ++i) {
        const int d = g * 4 + i * 32;
        const float4 w4 = *reinterpret_cast<const float4*>(&wsh[d]);
        const float4 b4 = *reinterpret_cast<const float4*>(&bsh[d]);
        v[i].x = (v[i].x - mu) * rstd * w4.x + b4.x;
        v[i].y = (v[i].y - mu) * rstd * w4.y + b4.y;
        v[i].z = (v[i].z - mu) * rstd * w4.z + b4.z;
        v[i].w = (v[i].w - mu) * rstd * w4.w + b4.w;
        if (doExp) {
            v[i].x = __expf(v[i].x); v[i].y = __expf(v[i].y);
            v[i].z = __expf(v[i].z); v[i].w = __expf(v[i].w);
            se += v[i].x + v[i].y + v[i].z + v[i].w;
        }
        h[i][0] = f2bf(v[i].x); h[i][1] = f2bf(v[i].y);
        h[i][2] = f2bf(v[i].z); h[i][3] = f2bf(v[i].w);
        int2 pk;
        pk.x = (int)((unsigned)h[i][0] | ((unsigned)h[i][1] << 16));
        pk.y = (int)((unsigned)h[i][2] | ((unsigned)h[i][3] << 16));
        *reinterpret_cast<int2*>(dst + row * Cc + d) = pk;
    }

    if (doExp) {
        se += __shfl_xor(se, 1); se += __shfl_xor(se, 2); se += __shfl_xor(se, 4);
        if (g == 0) rowsum[row] = se;
        // column partials: sum bf16-rounded values over the block's 64 n-rows.
#pragma unroll
        for (int i = 0; i < 8; ++i) {
            float c0 = bf2f(h[i][0]), c1 = bf2f(h[i][1]);
            float c2 = bf2f(h[i][2]), c3 = bf2f(h[i][3]);
#pragma unroll
            for (int m = 8; m <= 32; m <<= 1) {
                c0 += __shfl_xor(c0, m); c1 += __shfl_xor(c1, m);
                c2 += __shfl_xor(c2, m); c3 += __shfl_xor(c3, m);
            }
            if ((t & 63) < 8) {          // lane == g: holds wave-partial
                const int d = g * 4 + i * 32;
                wred[wv][d + 0] = c0; wred[wv][d + 1] = c1;
                wred[wv][d + 2] = c2; wred[wv][d + 3] = c3;
            }
        }
        __syncthreads();
        if (t < 256) {
            float ss = 0.f;
#pragma unroll
            for (int i = 0; i < 8; ++i) ss += wred[i][t];
            pS[((long long)b * 144 + nc) * Cc + t] = ss;
        }
    }
}

// ---------------- K_ctx2: ctx GEMM with transpose-on-load staging.
// ctxp[kc][b][d][e] = sum_{n in chunk} Kexp[n][d] * V[n][e], inputs row-major [n][*].
// grid (4, KS2=16, Bb): x = (d-tile<<1)|e-tile (128x128), block 256. BK=64 n, 9 iters.
__global__ __launch_bounds__(256) void k_ctx2(const u16* __restrict__ Kexp,
                                              const u16* __restrict__ V,
                                              float* __restrict__ ctxp) {
    __shared__ alignas(16) unsigned char smemRaw[32768];
    u16* Asm = reinterpret_cast<u16*>(smemRaw);            // [128 d][64 n] swizzled
    u16* Bsm = reinterpret_cast<u16*>(smemRaw + 16384);    // [128 e][64 n]
    float (*patch)[16][68] = reinterpret_cast<float (*)[16][68]>(smemRaw);

    const int t = threadIdx.x;
    const int b = blockIdx.z, kc = blockIdx.y;
    const int d0 = (blockIdx.x >> 1) * 128, e0 = (blockIdx.x & 1) * 128;
    const int l = t & 63, w = t >> 6;
    const int wr = w >> 1, wc = w & 1;
    const int frow = l & 15, fk = (l >> 4) << 3;
    const int sr = t & 63, sw = t >> 6;    // staging: n-row, wave(=64B line)

    f32x4 acc[4][4] = {};

    for (int kt = 0; kt < 9; ++kt) {
        const long long nb = (long long)b * Nn + kc * 576 + kt * 64;
        int4 av[4], bv[4];
#pragma unroll
        for (int j = 0; j < 4; ++j) {
            const int c8 = sw * 4 + j;     // 16B chunk 0..15 within 128-wide tile
            av[j] = *reinterpret_cast<const int4*>(Kexp + (nb + sr) * Cc + d0 + c8 * 8);
            bv[j] = *reinterpret_cast<const int4*>(V + (nb + sr) * Cc + e0 + c8 * 8);
        }
        __syncthreads();
#pragma unroll
        for (int j = 0; j < 4; ++j) {
            const u16* pa = reinterpret_cast<const u16*>(&av[j]);
            const u16* pb = reinterpret_cast<const u16*>(&bv[j]);
#pragma unroll
            for (int e8 = 0; e8 < 8; ++e8) {
                const int dd = (sw * 4 + j) * 8 + e8;
                const int col = sr ^ (e8 << 3);
                Asm[dd * 64 + col] = pa[e8];
                Bsm[dd * 64 + col] = pb[e8];
            }
        }
        __syncthreads();
#pragma unroll
        for (int kf = 0; kf < 2; ++kf) {
            short8 af[4], bf[4];
            const int kk = kf * 32 + fk;
#pragma unroll
            for (int mi = 0; mi < 4; ++mi) {
                const int rw_ = wr * 64 + mi * 16 + frow;
                af[mi] = *reinterpret_cast<const short8*>(&Asm[rw_ * 64 + (kk ^ ((rw_ & 7) << 3))]);
            }
#pragma unroll
            for (int ni = 0; ni < 4; ++ni) {
                const int rw_ = wc * 64 + ni * 16 + frow;
                bf[ni] = *reinterpret_cast<const short8*>(&Bsm[rw_ * 64 + (kk ^ ((rw_ & 7) << 3))]);
            }
#pragma unroll
            for (int mi = 0; mi < 4; ++mi)
#pragma unroll
                for (int ni = 0; ni < 4; ++ni)
                    acc[mi][ni] = __builtin_amdgcn_mfma_f32_16x16x32_bf16(af[mi], bf[ni], acc[mi][ni], 0, 0, 0);
        }
    }

    __syncthreads();
    float* Cg = ctxp + ((long long)kc * Bb + b) * Cc * Cc;
    const int crow0 = (l >> 4) * 4, ccol = l & 15;
#pragma unroll
    for (int mi = 0; mi < 4; ++mi) {
#pragma unroll
        for (int ni = 0; ni < 4; ++ni)
#pragma unroll
            for (int r_ = 0; r_ < 4; ++r_)
                patch[w][crow0 + r_][ni * 16 + ccol] = acc[mi][ni][r_];
        asm volatile("s_waitcnt lgkmcnt(0)" ::: "memory");
        __builtin_amdgcn_sched_barrier(0);
#pragma unroll
        for (int row = 0; row < 16; ++row)
            Cg[(long long)(d0 + wr * 64 + mi * 16 + row) * Cc + e0 + wc * 64 + l] = patch[w][row][l];
        asm volatile("s_waitcnt lgkmcnt(0)" ::: "memory");
        __builtin_amdgcn_sched_barrier(0);
    }
}

// ---------------- K4: fused {colS reduce + split-K reduce + scale + rank + top-k coeffs}.
// block per (b,d) row.
__global__ __launch_bounds__(256) void k_rankred(const float* __restrict__ ctxp,
                                                 const float* __restrict__ pS,
                                                 const float* __restrict__ aw,
                                                 float* __restrict__ Ac) {
    __shared__ float row[256];
    __shared__ float red[256];
    const int d = blockIdx.x, b = blockIdx.y, e = threadIdx.x;

    // colS[b][d] = sum over 144 pS chunks (tree reduce; L2-served reads)
    red[e] = (e < 144) ? pS[((long long)b * 144 + e) * Cc + d] : 0.f;
    __syncthreads();
    for (int s_ = 128; s_; s_ >>= 1) { if (e < s_) red[e] += red[e + s_]; __syncthreads(); }
    const float invCol = 1.0f / red[0];
    __syncthreads();

    float c = 0.f;
#pragma unroll
    for (int kc = 0; kc < KS2; ++kc)
        c += ctxp[(((long long)kc * Bb + b) * Cc + d) * Cc + e];
    c *= invCol;
    row[e] = c;
    __syncthreads();
    int p = 0;
    for (int j = 0; j < 256; ++j) {
        const float cj = row[j];
        p += (cj > c) || (cj == c && j < e);  // stable top_k rank (0-based)
    }
    red[e] = c; __syncthreads();
    for (int s_ = 128; s_; s_ >>= 1) { if (e < s_) red[e] = fmaxf(red[e], red[e + s_]); __syncthreads(); }
    const float m = red[0];
    const float ex = __expf(c - m);
    const int kks[4] = {128, 170, 192, 204};
    float Zv[4];
#pragma unroll
    for (int i = 0; i < 4; ++i) {
        __syncthreads();
        red[e] = (p < kks[i]) ? ex : 0.0f;
        __syncthreads();
        for (int s_ = 128; s_; s_ >>= 1) { if (e < s_) red[e] += red[e + s_]; __syncthreads(); }
        Zv[i] = red[0];
    }
    float wsum = 0.0f;
#pragma unroll
    for (int i = 0; i < 4; ++i)
        if (p < kks[i]) wsum += aw[i] / Zv[i];
    Ac[((long long)(b * Cc + d)) * Cc + e] = ex * wsum;
}

// ---------------- K5: WA[b,o,e] = sum_d W[o,d] * A[b,d,e] -> bf16. grid (32, 8), block 256.
__global__ __launch_bounds__(256) void k_wa(const float* __restrict__ W,
                                            const float* __restrict__ Ac,
                                            u16* __restrict__ WAb16) {
    __shared__ float As[16][64], Bs[16][64];
    const int b = blockIdx.y;
    const int o0 = (blockIdx.x >> 2) * 64, e0 = (blockIdx.x & 3) * 64;
    const int t = threadIdx.x, tx = t & 15, ty = t >> 4;
    const int a_oo = t >> 2, a_k4 = (t & 3) * 4;
    const int b_kk = t >> 4, b_e4 = (t & 15) * 4;
    float acc[4][4] = {{0.f}};
    for (int kd = 0; kd < 256; kd += 16) {
        const float4 wv = *reinterpret_cast<const float4*>(W + (o0 + a_oo) * Cc + kd + a_k4);
        const float4 av = *reinterpret_cast<const float4*>(Ac + ((long long)(b * Cc + kd + b_kk)) * Cc + e0 + b_e4);
        __syncthreads();
        As[a_k4 + 0][a_oo] = wv.x; As[a_k4 + 1][a_oo] = wv.y;
        As[a_k4 + 2][a_oo] = wv.z; As[a_k4 + 3][a_oo] = wv.w;
        *reinterpret_cast<float4*>(&Bs[b_kk][b_e4]) = av;
        __syncthreads();
#pragma unroll
        for (int kk = 0; kk < 16; ++kk) {
            const float4 a4 = *reinterpret_cast<const float4*>(&As[kk][ty * 4]);
            const float4 b4 = *reinterpret_cast<const float4*>(&Bs[kk][tx * 4]);
            const float aa[4] = {a4.x, a4.y, a4.z, a4.w};
            const float bb[4] = {b4.x, b4.y, b4.z, b4.w};
#pragma unroll
            for (int i = 0; i < 4; ++i)
#pragma unroll
                for (int j = 0; j < 4; ++j) acc[i][j] = fmaf(aa[i], bb[j], acc[i][j]);
        }
    }
#pragma unroll
    for (int i = 0; i < 4; ++i) {
        int2 pk;
        pk.x = (int)((unsigned)f2bf(acc[i][0]) | ((unsigned)f2bf(acc[i][1]) << 16));
        pk.y = (int)((unsigned)f2bf(acc[i][2]) | ((unsigned)f2bf(acc[i][3]) << 16));
        *reinterpret_cast<int2*>(WAb16 + ((long long)(b * Oo + o0 + ty * 4 + i)) * Cc + e0 + tx * 4) = pk;
    }
}

// ---------------- K7: fused reprojection GEMM + row-scale + bias + LN(512) + transposed store.
// A = Kexp (unnormalized); softmax row-normalization pulled into the f32 epilogue.
// grid (288, 1, 8), block 256 (4 waves x 128 o), XCD-swizzled n-tiles, nt stores.
__global__ __launch_bounds__(256, 3) void k_rpln(const u16* __restrict__ Kexp,
                                                 const float* __restrict__ rowsum,
                                                 const u16* __restrict__ WAb16,
                                                 const float* __restrict__ rbias,
                                                 const float* __restrict__ nw,
                                                 const float* __restrict__ nb,
                                                 float* __restrict__ out) {
    __shared__ float patch[4][16][36];          // per-wave 16 o x 32 n
    __shared__ float psum[32][4], psq[32][4];
    __shared__ float muA[32], rsA[32];
    __shared__ float irow[32];

    const int t = threadIdx.x;
    const int b = blockIdx.z;
    const int nt_ = (blockIdx.x & 7) * 36 + (blockIdx.x >> 3);   // XCD swizzle (288 = 8*36)
    const int n0 = nt_ * 32;
    const int l = t & 63, w = t >> 6;           // wave w owns o = w*128..
    const int frow = l & 15, fk = (l >> 4) << 3;
    const int hi = l >> 4;

    if (t < 32) irow[t] = 1.0f / rowsum[(long long)b * Nn + n0 + t];

    f32x4 acc[2][8] = {};

    const u16* Aq = Kexp + ((long long)b * Nn + n0) * Cc;
    const u16* Bw = WAb16 + ((long long)b * Oo + w * 128) * Cc;

    // preload ALL A fragments: 2 n-halves x 8 K-steps
    int4 aF[2][8];
#pragma unroll
    for (int mi = 0; mi < 2; ++mi)
#pragma unroll
        for (int s = 0; s < 8; ++s)
            aF[mi][s] = *reinterpret_cast<const int4*>(Aq + (mi * 16 + frow) * Cc + s * 32 + fk);

    int4 bC[8], bN[8];
#pragma unroll
    for (int ni = 0; ni < 8; ++ni)
        bC[ni] = *reinterpret_cast<const int4*>(Bw + (ni * 16 + frow) * Cc + fk);

#pragma unroll
    for (int s = 0; s < 8; ++s) {
        if (s < 7) {
            const int kk = (s + 1) * 32 + fk;
#pragma unroll
            for (int ni = 0; ni < 8; ++ni)
                bN[ni] = *reinterpret_cast<const int4*>(Bw + (ni * 16 + frow) * Cc + kk);
        }
#pragma unroll
        for (int mi = 0; mi < 2; ++mi)
#pragma unroll
            for (int ni = 0; ni < 8; ++ni)
                acc[mi][ni] = __builtin_amdgcn_mfma_f32_16x16x32_bf16(
                    __builtin_bit_cast(short8, aF[mi][s]), __builtin_bit_cast(short8, bC[ni]),
                    acc[mi][ni], 0, 0, 0);
        if (s < 7) {
#pragma unroll
            for (int ni = 0; ni < 8; ++ni) bC[ni] = bN[ni];
        }
    }

    __syncthreads();   // irow visible
    // ---- epilogue: row-scale (softmax denominator) + bias
#pragma unroll
    for (int ni = 0; ni < 8; ++ni) {
        const float bb = rbias[w * 128 + ni * 16 + frow];
#pragma unroll
        for (int mi = 0; mi < 2; ++mi)
#pragma unroll
            for (int r_ = 0; r_ < 4; ++r_) {
                const int rw_ = mi * 16 + hi * 4 + r_;
                acc[mi][ni][r_] = acc[mi][ni][r_] * irow[rw_] + bb;
            }
    }
    // per-row LN partials over this wave's 128 cols
#pragma unroll
    for (int mi = 0; mi < 2; ++mi)
#pragma unroll
        for (int r_ = 0; r_ < 4; ++r_) {
            float s = 0.f, q = 0.f;
#pragma unroll
            for (int ni = 0; ni < 8; ++ni) { const float v = acc[mi][ni][r_]; s += v; q += v * v; }
#pragma unroll
            for (int m = 8; m; m >>= 1) { s += __shfl_xor(s, m); q += __shfl_xor(q, m); }
            if (frow == 0) {
                const int row = mi * 16 + hi * 4 + r_;
                psum[row][w] = s; psq[row][w] = q;
            }
        }
    __syncthreads();
    if (t < 32) {
        const float s = psum[t][0] + psum[t][1] + psum[t][2] + psum[t][3];
        const float q = psq[t][0] + psq[t][1] + psq[t][2] + psq[t][3];
        const float m = s * (1.0f / Oo);
        muA[t] = m;
        rsA[t] = rsqrtf(q * (1.0f / Oo) - m * m + LN_EPS);
    }
    __syncthreads();

    float nwv[8], nbv[8];
#pragma unroll
    for (int ni = 0; ni < 8; ++ni) {
        const int o = w * 128 + ni * 16 + frow;
        nwv[ni] = nw[o]; nbv[ni] = nb[o];
    }

    // per ni: wave-private 16o x 32n patch -> nontemporal f32x4 stores.
#pragma unroll
    for (int ni = 0; ni < 8; ++ni) {
#pragma unroll
        for (int mi = 0; mi < 2; ++mi)
#pragma unroll
            for (int r_ = 0; r_ < 4; ++r_) {
                const int nl = mi * 16 + hi * 4 + r_;              // 0..31
                patch[w][frow][nl] = (acc[mi][ni][r_] - muA[nl]) * rsA[nl] * nwv[ni] + nbv[ni];
            }
        asm volatile("s_waitcnt lgkmcnt(0)" ::: "memory");
        __builtin_amdgcn_sched_barrier(0);
#pragma unroll
        for (int p = 0; p < 2; ++p) {
            const int o_loc = p * 8 + (l >> 3);                    // 0..15
            const int colf4 = l & 7;                               // 0..7
            const f32x4 v = *reinterpret_cast<const f32x4*>(&patch[w][o_loc][colf4 * 4]);
            const int o_g = w * 128 + ni * 16 + o_loc;
            __builtin_nontemporal_store(v,
                reinterpret_cast<f32x4*>(&out[((long long)(b * Oo + o_g)) * Nn + n0 + colf4 * 4]));
        }
        asm volatile("s_waitcnt lgkmcnt(0)" ::: "memory");
        __builtin_amdgcn_sched_barrier(0);
    }
}

extern "C" void kernel_launch(void* const* d_in, const int* in_sizes, int n_in,
                              void* d_out, int out_size, void* d_ws, size_t ws_size,
                              hipStream_t stream) {
    (void)in_sizes; (void)n_in; (void)out_size; (void)ws_size;
    const float* x1    = (const float*)d_in[0];
    const float* x2    = (const float*)d_in[1];
    const float* n1w   = (const float*)d_in[2];
    const float* n1b   = (const float*)d_in[3];
    const float* rw    = (const float*)d_in[4];
    const float* rbias = (const float*)d_in[5];
    const float* n2w   = (const float*)d_in[6];
    const float* n2b   = (const float*)d_in[7];
    const float* aw    = (const float*)d_in[8];
    float* out = (float*)d_out;

    // d_out doubles as scratch for V (dead before k_rpln's final overwrite).
    u16* V = (u16*)d_out;

    float* ws = (float*)d_ws;
    size_t off = 0;
    u16*   Kexp   = (u16*)(ws + off); off += (size_t)Bb * Nn * Cc / 2;
    float* ctxp   = ws + off; off += (size_t)KS2 * Bb * Cc * Cc;
    float* Ac     = ws + off; off += (size_t)Bb * Cc * Cc;
    u16*   WAb16  = (u16*)(ws + off); off += (size_t)Bb * Oo * Cc / 2;
    float* pS     = ws + off; off += (size_t)Bb * 144 * Cc;
    float* rowsum = ws + off; off += (size_t)Bb * Nn;

    k_pre<<<dim3(144, 2, Bb), 512, 0, stream>>>(x2, x1, n1w, n1b, Kexp, V, rowsum, pS);
    k_ctx2<<<dim3(4, KS2, Bb), 256, 0, stream>>>(Kexp, V, ctxp);
    k_rankred<<<dim3(Cc, Bb), 256, 0, stream>>>(ctxp, pS, aw, Ac);
    k_wa<<<dim3(32, Bb), 256, 0, stream>>>(rw, Ac, WAb16);
    k_rpln<<<dim3(288, 1, Bb), 256, 0, stream>>>(Kexp, rowsum, WAb16, rbias, n2w, n2b, out);
}